// Round 8
// baseline (1182.621 us; speedup 1.0000x reference)
//
#include <hip/hip_runtime.h>
#include <hip/hip_bf16.h>

#define B_    16
#define FEA_  512
#define DM_   1024
#define HALF_ 512
#define DFF_  2048

typedef unsigned short u16;
typedef __attribute__((ext_vector_type(8))) short bf16x8;
typedef __attribute__((ext_vector_type(4))) float f32x4;

__device__ __forceinline__ float bf2f(u16 u) {
  union { unsigned int i; float f; } v; v.i = ((unsigned int)u) << 16; return v.f;
}
__device__ __forceinline__ u16 f2bf(float f) {
  union { float f; unsigned int i; } v; v.f = f;
  unsigned int x = v.i;
  return (u16)((x + 0x7fffu + ((x >> 16) & 1u)) >> 16);
}
__device__ __forceinline__ void gload16(const u16* g, u16* l) {
  __builtin_amdgcn_global_load_lds(
      (const __attribute__((address_space(1))) void*)g,
      (__attribute__((address_space(3))) void*)l, 16, 0, 0);
}

// ---------------- DWT (Haar, level 1, last axis) ----------------
__global__ void dwt_kernel(const float* __restrict__ x, u16* __restrict__ x1,
                           u16* __restrict__ x2, int n) {
  int i = blockIdx.x * 256 + threadIdx.x;
  if (i >= n) return;
  float2 v = ((const float2*)x)[i];
  x1[i] = f2bf((v.x + v.y) * 0.70710678118f);
  x2[i] = f2bf((v.x - v.y) * 0.70710678118f);
}

// ---------------- weight transpose (Cout,Cin,3) -> bf16 (3,Cout,Cin) ----------------
__global__ void wtrans_kernel(const float* __restrict__ w, u16* __restrict__ wt,
                              int Cout, int Cin) {
  int e = blockIdx.x * 256 + threadIdx.x;
  if (e >= Cout * Cin * 3) return;
  int co = e / (Cin * 3);
  int r  = e - co * Cin * 3;
  int ci = r / 3;
  int t  = r - ci * 3;
  wt[((size_t)t * Cout + co) * Cin + ci] = f2bf(w[e]);
}

// ---------------- circular conv1d (k=3) as MFMA GEMM ----------------
// 1-D grid, co-tile-major decode: lin % nco = co_tile => XCD (= lin%8 round
// robin) serves 1-2 fixed co-tiles -> weights L2-resident. Chunked K-loop
// (chunk = ci-group x tap), Ws double-buffered via global_load_lds (swizzle on
// the global source), Zs reg-staged. Vectorized ushort4 store when osl==1.
__global__ __launch_bounds__(256, 3) void conv_mfma_kernel(
    const u16* __restrict__ Z, const u16* __restrict__ Wt,
    const float* __restrict__ bias, u16* __restrict__ out,
    int L, int Cin, int Cout, int osl, int osc, int relu) {
  __shared__ u16 Zs[130][64];
  __shared__ u16 Wb[2][128][64];
  int nco = Cout >> 7, nl = L >> 7;
  int lin = blockIdx.x;
  int co_t = lin % nco;
  int rest = lin / nco;
  int l_t = rest % nl;
  int b = rest / nl;
  int l0 = l_t * 128, co0 = co_t * 128;
  int tid = threadIdx.x;
  int lane = tid & 63, w = tid >> 6, wr = w >> 1, wc = w & 1;
  int row16 = lane & 15, g4 = lane >> 4;
  f32x4 acc[4][4];
#pragma unroll
  for (int i = 0; i < 4; ++i)
#pragma unroll
    for (int j = 0; j < 4; ++j) acc[i][j] = (f32x4){0.f, 0.f, 0.f, 0.f};
  const u16* Zb = Z + (size_t)b * L * Cin;

  uint4 zr[5];
  auto zs_issue = [&](int c0) {
#pragma unroll
    for (int i = 0; i < 5; ++i) {
      int e = tid + i * 256;
      if (e < 130 * 8) {
        int r = e >> 3, c = e & 7;
        int gl = l0 + r - 1;
        if (gl < 0) gl += L; else if (gl >= L) gl -= L;
        zr[i] = *(const uint4*)(Zb + (size_t)gl * Cin + c0 + c * 8);
      }
    }
  };
  auto zs_write = [&]() {
#pragma unroll
    for (int i = 0; i < 5; ++i) {
      int e = tid + i * 256;
      if (e < 130 * 8) {
        int r = e >> 3, c = e & 7;
        *(uint4*)&Zs[r][(c ^ (r & 7)) * 8] = zr[i];
      }
    }
  };
  auto ws_issue = [&](int t, int c0, int buf) {
    const u16* Wg = Wt + ((size_t)t * Cout + co0) * Cin + c0;
    int c = lane & 7;
#pragma unroll
    for (int i = 0; i < 4; ++i) {
      int rw = (i * 4 + w) * 8 + (lane >> 3);
      gload16(Wg + (size_t)rw * Cin + ((c ^ (rw & 7)) * 8), &Wb[buf][(i * 4 + w) * 8][0]);
    }
  };

  int nchunk = (Cin >> 6) * 3;
  zs_issue(0);
  zs_write();
  ws_issue(0, 0, 0);
  __syncthreads();

  for (int k = 0; k < nchunk; ++k) {
    int t = k % 3;
    int c0 = (k / 3) << 6;
    int cur = k & 1;
    if (k + 1 < nchunk) ws_issue((k + 1) % 3, ((k + 1) / 3) << 6, cur ^ 1);
    bool bndry = (t == 2) && (c0 + 64 < Cin);
    if (bndry) zs_issue(c0 + 64);
#pragma unroll
    for (int ks = 0; ks < 2; ++ks) {
      int s = ks * 4 + g4;   // 16B slot index within row
      bf16x8 af[4], bfr[4];
#pragma unroll
      for (int mi = 0; mi < 4; ++mi) {
        int ra = wr * 64 + mi * 16 + row16 + t;
        af[mi] = *(const bf16x8*)&Zs[ra][(s ^ (ra & 7)) * 8];
      }
#pragma unroll
      for (int ni = 0; ni < 4; ++ni) {
        int rb = wc * 64 + ni * 16 + row16;
        bfr[ni] = *(const bf16x8*)&Wb[cur][rb][(s ^ (rb & 7)) * 8];
      }
#pragma unroll
      for (int mi = 0; mi < 4; ++mi)
#pragma unroll
        for (int ni = 0; ni < 4; ++ni)
          acc[mi][ni] = __builtin_amdgcn_mfma_f32_16x16x32_bf16(
              af[mi], bfr[ni], acc[mi][ni], 0, 0, 0);
    }
    __syncthreads();
    if (bndry) {
      zs_write();
      __syncthreads();
    }
  }

  size_t ob = (size_t)b * L * Cout;
  if (osl == 1) {
    // output contiguous in l: 4 acc elements = 4 consecutive l -> ushort4 store
#pragma unroll
    for (int ni = 0; ni < 4; ++ni) {
      int co = co0 + wc * 64 + ni * 16 + row16;
      float bz = bias[co];
#pragma unroll
      for (int mi = 0; mi < 4; ++mi) {
        int l = l0 + wr * 64 + mi * 16 + g4 * 4;
        ushort4 pk;
        float v0 = acc[mi][ni][0] + bz, v1 = acc[mi][ni][1] + bz;
        float v2 = acc[mi][ni][2] + bz, v3 = acc[mi][ni][3] + bz;
        if (relu) { v0 = fmaxf(v0, 0.f); v1 = fmaxf(v1, 0.f); v2 = fmaxf(v2, 0.f); v3 = fmaxf(v3, 0.f); }
        pk.x = f2bf(v0); pk.y = f2bf(v1); pk.z = f2bf(v2); pk.w = f2bf(v3);
        *(ushort4*)(out + ob + (size_t)co * osc + l) = pk;
      }
    }
  } else {
#pragma unroll
    for (int ni = 0; ni < 4; ++ni) {
      int co = co0 + wc * 64 + ni * 16 + row16;
      float bz = bias[co];
#pragma unroll
      for (int mi = 0; mi < 4; ++mi) {
#pragma unroll
        for (int r = 0; r < 4; ++r) {
          int l = l0 + wr * 64 + mi * 16 + g4 * 4 + r;
          float v = acc[mi][ni][r] + bz;
          if (relu) v = fmaxf(v, 0.f);
          out[ob + (size_t)l * osl + (size_t)co * osc] = f2bf(v);
        }
      }
    }
  }
}

// ---------------- fused cross attention, MFMA (unchanged) ----------------
__global__ __launch_bounds__(256, 4) void attn_mfma_kernel(
    const u16* __restrict__ qh, const u16* __restrict__ kh, const u16* __restrict__ vhT,
    const u16* __restrict__ ql, const u16* __restrict__ kl, const u16* __restrict__ vlT,
    u16* __restrict__ ctx) {
  __shared__ u16 Qs[64][72], Ks[64][72], Vts[64][72];
  __shared__ u16 Ps[64][72];
  __shared__ float rsl[2][2][32];
  int qt = blockIdx.x, h = blockIdx.y, bz = blockIdx.z;
  int b = bz >> 1, br = bz & 1;
  const u16* Q  = br ? ql  : qh;
  const u16* K  = br ? kh  : kl;
  const u16* Vt = br ? vlT : vhT;
  int tid = threadIdx.x;
  int lane = tid & 63, w = tid >> 6, wr = w >> 1, wc = w & 1;
  int row16 = lane & 15, g4 = lane >> 4, k8 = g4 * 8;
  int q0 = qt * 64;
  size_t baseQK = (size_t)b * FEA_ * DM_ + h * 64;
  size_t baseV  = (size_t)b * DM_ * FEA_ + (size_t)(h * 64) * FEA_;
  for (int e = tid; e < 64 * 8; e += 256) {
    int r = e >> 3, c = e & 7;
    *(uint4*)&Qs[r][c * 8] = *(const uint4*)(Q + baseQK + (size_t)(q0 + r) * DM_ + c * 8);
  }
  f32x4 oacc[2][2];
  float rsum[2][4];
#pragma unroll
  for (int i = 0; i < 2; ++i) {
#pragma unroll
    for (int j = 0; j < 2; ++j) oacc[i][j] = (f32x4){0.f, 0.f, 0.f, 0.f};
#pragma unroll
    for (int r = 0; r < 4; ++r) rsum[i][r] = 0.f;
  }
  for (int kt = 0; kt < 8; ++kt) {
    __syncthreads();
    for (int e = tid; e < 64 * 8; e += 256) {
      int r = e >> 3, c = e & 7;
      *(uint4*)&Ks[r][c * 8]  = *(const uint4*)(K + baseQK + (size_t)(kt * 64 + r) * DM_ + c * 8);
      *(uint4*)&Vts[r][c * 8] = *(const uint4*)(Vt + baseV + (size_t)r * FEA_ + kt * 64 + c * 8);
    }
    __syncthreads();
    f32x4 sacc[2][2];
#pragma unroll
    for (int i = 0; i < 2; ++i)
#pragma unroll
      for (int j = 0; j < 2; ++j) sacc[i][j] = (f32x4){0.f, 0.f, 0.f, 0.f};
#pragma unroll
    for (int ks = 0; ks < 2; ++ks) {
      int k0 = ks * 32 + k8;
      bf16x8 a0 = *(const bf16x8*)&Qs[wr * 32 + row16][k0];
      bf16x8 a1 = *(const bf16x8*)&Qs[wr * 32 + 16 + row16][k0];
      bf16x8 b0 = *(const bf16x8*)&Ks[wc * 32 + row16][k0];
      bf16x8 b1 = *(const bf16x8*)&Ks[wc * 32 + 16 + row16][k0];
      sacc[0][0] = __builtin_amdgcn_mfma_f32_16x16x32_bf16(a0, b0, sacc[0][0], 0, 0, 0);
      sacc[0][1] = __builtin_amdgcn_mfma_f32_16x16x32_bf16(a0, b1, sacc[0][1], 0, 0, 0);
      sacc[1][0] = __builtin_amdgcn_mfma_f32_16x16x32_bf16(a1, b0, sacc[1][0], 0, 0, 0);
      sacc[1][1] = __builtin_amdgcn_mfma_f32_16x16x32_bf16(a1, b1, sacc[1][1], 0, 0, 0);
    }
#pragma unroll
    for (int mi = 0; mi < 2; ++mi)
#pragma unroll
      for (int ni = 0; ni < 2; ++ni)
#pragma unroll
        for (int r = 0; r < 4; ++r) {
          float p = __expf(sacc[mi][ni][r] * 0.25f);
          rsum[mi][r] += p;
          Ps[wr * 32 + mi * 16 + g4 * 4 + r][wc * 32 + ni * 16 + row16] = f2bf(p);
        }
    __syncthreads();
#pragma unroll
    for (int ks = 0; ks < 2; ++ks) {
      int k0 = ks * 32 + k8;
      bf16x8 a0 = *(const bf16x8*)&Ps[wr * 32 + row16][k0];
      bf16x8 a1 = *(const bf16x8*)&Ps[wr * 32 + 16 + row16][k0];
      bf16x8 b0 = *(const bf16x8*)&Vts[wc * 32 + row16][k0];
      bf16x8 b1 = *(const bf16x8*)&Vts[wc * 32 + 16 + row16][k0];
      oacc[0][0] = __builtin_amdgcn_mfma_f32_16x16x32_bf16(a0, b0, oacc[0][0], 0, 0, 0);
      oacc[0][1] = __builtin_amdgcn_mfma_f32_16x16x32_bf16(a0, b1, oacc[0][1], 0, 0, 0);
      oacc[1][0] = __builtin_amdgcn_mfma_f32_16x16x32_bf16(a1, b0, oacc[1][0], 0, 0, 0);
      oacc[1][1] = __builtin_amdgcn_mfma_f32_16x16x32_bf16(a1, b1, oacc[1][1], 0, 0, 0);
    }
  }
#pragma unroll
  for (int mi = 0; mi < 2; ++mi)
#pragma unroll
    for (int r = 0; r < 4; ++r) {
#pragma unroll
      for (int m = 1; m < 16; m <<= 1) rsum[mi][r] += __shfl_xor(rsum[mi][r], m);
    }
  if (row16 == 0) {
#pragma unroll
    for (int mi = 0; mi < 2; ++mi)
#pragma unroll
      for (int r = 0; r < 4; ++r) rsl[wr][wc][mi * 16 + g4 * 4 + r] = rsum[mi][r];
  }
  __syncthreads();
#pragma unroll
  for (int mi = 0; mi < 2; ++mi)
#pragma unroll
    for (int ni = 0; ni < 2; ++ni)
#pragma unroll
      for (int r = 0; r < 4; ++r) {
        int qq = mi * 16 + g4 * 4 + r;
        float denom = rsl[wr][0][qq] + rsl[wr][1][qq];
        float o = oacc[mi][ni][r] / denom;
        Ps[wc * 32 + ni * 16 + row16][wr * 32 + qq] = f2bf(o);
      }
  __syncthreads();
  for (int e = tid; e < 64 * 8; e += 256) {
    int r = e >> 3, c = e & 7;
    size_t dst = ((size_t)b * DM_ + h * 64 + r) * (2 * FEA_) + br * 512 + q0 + c * 8;
    *(uint4*)(ctx + dst) = *(const uint4*)&Ps[r][c * 8];
  }
}

// ---------------- LayerNorm over last axis (+optional f32 residual out) ----------------
template <int RESID>
__global__ void ln_kernel(const u16* __restrict__ in, const float* __restrict__ g,
                          const float* __restrict__ beta, const float* __restrict__ resid,
                          void* __restrict__ outp, int C) {
  int row = blockIdx.x;
  int tid = threadIdx.x;
  const u16* p = in + (size_t)row * C;
  float s = 0.f, ss = 0.f;
  for (int c = tid; c < C; c += 256) {
    float v = bf2f(p[c]);
    s += v; ss += v * v;
  }
#pragma unroll
  for (int m = 1; m < 64; m <<= 1) { s += __shfl_xor(s, m); ss += __shfl_xor(ss, m); }
  __shared__ float red[2][4];
  int wid = tid >> 6, lane = tid & 63;
  if (lane == 0) { red[0][wid] = s; red[1][wid] = ss; }
  __syncthreads();
  s  = red[0][0] + red[0][1] + red[0][2] + red[0][3];
  ss = red[1][0] + red[1][1] + red[1][2] + red[1][3];
  float m  = s / C;
  float var = ss / C - m * m;
  float inv = rsqrtf(var + 1e-5f);
  for (int c = tid; c < C; c += 256) {
    float v = (bf2f(p[c]) - m) * inv * g[c] + beta[c];
    if (RESID) ((float*)outp)[(size_t)row * C + c] = v + resid[(size_t)row * C + c];
    else       ((u16*)outp)[(size_t)row * C + c]   = f2bf(v);
  }
}

extern "C" void kernel_launch(void* const* d_in, const int* in_sizes, int n_in,
                              void* d_out, int out_size, void* d_ws, size_t ws_size,
                              hipStream_t stream) {
  (void)in_sizes; (void)n_in; (void)out_size; (void)ws_size;
  const float* x      = (const float*)d_in[0];
  const float* Wq     = (const float*)d_in[1];
  const float* bq     = (const float*)d_in[2];
  const float* Wk     = (const float*)d_in[3];
  const float* bk     = (const float*)d_in[4];
  const float* Wv     = (const float*)d_in[5];
  const float* bv     = (const float*)d_in[6];
  const float* uns_w  = (const float*)d_in[7];
  const float* uns_b  = (const float*)d_in[8];
  const float* cv_w1  = (const float*)d_in[9];
  const float* cv_b1  = (const float*)d_in[10];
  const float* cv_w2  = (const float*)d_in[11];
  const float* cv_b2  = (const float*)d_in[12];
  const float* cv_g   = (const float*)d_in[13];
  const float* cv_beta= (const float*)d_in[14];
  const float* up_w1  = (const float*)d_in[15];
  const float* up_b1  = (const float*)d_in[16];
  const float* up_w2  = (const float*)d_in[17];
  const float* up_b2  = (const float*)d_in[18];
  const float* up_g   = (const float*)d_in[19];
  const float* up_beta= (const float*)d_in[20];

  // ---- workspace plan (peak 112 MiB of d_ws; d_out doubles as scratch) ----
  char* ws = (char*)d_ws;
  const size_t MB = 1ull << 20;
  u16* x1    = (u16*)(ws + 0);
  u16* x2    = (u16*)(ws + 8 * MB);
  u16* qhb   = (u16*)(ws + 16 * MB);
  u16* khb   = (u16*)(ws + 32 * MB);
  u16* vhb   = (u16*)(ws + 48 * MB);   // stored TRANSPOSED: [b][d][fea]
  u16* qlb   = (u16*)(ws + 64 * MB);
  u16* klb   = (u16*)(ws + 80 * MB);
  u16* vlb   = (u16*)(ws + 96 * MB);   // stored TRANSPOSED: [b][d][fea]
  u16* wt_proj = (u16*)d_out;
  u16* ctx   = (u16*)d_out;
  u16* wt_uns = (u16*)(ws + 0);
  u16* ctx2  = (u16*)(ws + 16 * MB);
  u16* wt_cv1 = (u16*)(ws + 32 * MB);
  u16* h1    = (u16*)(ws + 56 * MB);
  u16* wt_cv2 = (u16*)(ws + 32 * MB);
  u16* h2    = (u16*)(ws + 0);
  u16* ctx3  = (u16*)(ws + 8 * MB);
  u16* wt_up1 = (u16*)(ws + 16 * MB);
  u16* h3    = (u16*)(ws + 32 * MB);
  u16* wt_up2 = (u16*)(ws + 64 * MB);
  u16* h4    = (u16*)(ws + 16 * MB);

  dwt_kernel<<<(B_ * FEA_ * HALF_ + 255) / 256, 256, 0, stream>>>(x, x1, x2, B_ * FEA_ * HALF_);

  auto wtr = [&](const float* w, u16* wt, int Cout, int Cin) {
    wtrans_kernel<<<(Cout * Cin * 3 + 255) / 256, 256, 0, stream>>>(w, wt, Cout, Cin);
  };
  auto conv = [&](const u16* Z, const u16* wt, const float* bias, u16* out, int L,
                  int Cin, int Cout, int osl, int osc, int relu) {
    int nblk = (L >> 7) * (Cout >> 7) * B_;
    conv_mfma_kernel<<<nblk, 256, 0, stream>>>(Z, wt, bias, out, L, Cin, Cout, osl, osc, relu);
  };

  // projections (shared weights across both DWT branches); V written transposed
  wtr(Wq, wt_proj, DM_, HALF_);
  conv(x1, wt_proj, bq, qhb, FEA_, HALF_, DM_, DM_, 1, 0);
  conv(x2, wt_proj, bq, qlb, FEA_, HALF_, DM_, DM_, 1, 0);
  wtr(Wk, wt_proj, DM_, HALF_);
  conv(x1, wt_proj, bk, khb, FEA_, HALF_, DM_, DM_, 1, 0);
  conv(x2, wt_proj, bk, klb, FEA_, HALF_, DM_, DM_, 1, 0);
  wtr(Wv, wt_proj, DM_, HALF_);
  conv(x1, wt_proj, bv, vhb, FEA_, HALF_, DM_, 1, FEA_, 0);
  conv(x2, wt_proj, bv, vlb, FEA_, HALF_, DM_, 1, FEA_, 0);

  attn_mfma_kernel<<<dim3(8, 16, 32), 256, 0, stream>>>(qhb, khb, vhb, qlb, klb, vlb, ctx);

  // unsqueeze conv: conv along d axis, channels 2F->F, transposed write -> ctx2[b][f][d]
  wtr(uns_w, wt_uns, FEA_, 2 * FEA_);
  conv(ctx, wt_uns, uns_b, ctx2, DM_, 2 * FEA_, FEA_, 1, DM_, 0);

  // Convlayer: D_MODEL -> D_FF -> HALF (conv along fea axis), then LN
  wtr(cv_w1, wt_cv1, DFF_, DM_);
  conv(ctx2, wt_cv1, cv_b1, h1, FEA_, DM_, DFF_, DFF_, 1, 1);
  wtr(cv_w2, wt_cv2, HALF_, DFF_);
  conv(h1, wt_cv2, cv_b2, h2, FEA_, DFF_, HALF_, HALF_, 1, 0);
  ln_kernel<0><<<B_ * FEA_, 256, 0, stream>>>(h2, cv_g, cv_beta, nullptr, ctx3, HALF_);

  // upsizeConvlayer: HALF -> D_FF -> D_MODEL, then LN + residual
  wtr(up_w1, wt_up1, DFF_, HALF_);
  conv(ctx3, wt_up1, up_b1, h3, FEA_, HALF_, DFF_, DFF_, 1, 1);
  wtr(up_w2, wt_up2, DM_, DFF_);
  conv(h3, wt_up2, up_b2, h4, FEA_, DFF_, DM_, DM_, 1, 0);
  ln_kernel<1><<<B_ * FEA_, 256, 0, stream>>>(h4, up_g, up_beta, x, d_out, DM_);
}

// Round 9
// 1147.413 us; speedup vs baseline: 1.0307x; 1.0307x over previous
//
#include <hip/hip_runtime.h>
#include <hip/hip_bf16.h>

#define B_    16
#define FEA_  512
#define DM_   1024
#define HALF_ 512
#define DFF_  2048

typedef unsigned short u16;
typedef __attribute__((ext_vector_type(8))) short bf16x8;
typedef __attribute__((ext_vector_type(4))) float f32x4;

__device__ __forceinline__ float bf2f(u16 u) {
  union { unsigned int i; float f; } v; v.i = ((unsigned int)u) << 16; return v.f;
}
__device__ __forceinline__ u16 f2bf(float f) {
  union { float f; unsigned int i; } v; v.f = f;
  unsigned int x = v.i;
  return (u16)((x + 0x7fffu + ((x >> 16) & 1u)) >> 16);
}
__device__ __forceinline__ void gload16(const u16* g, u16* l) {
  __builtin_amdgcn_global_load_lds(
      (const __attribute__((address_space(1))) void*)g,
      (__attribute__((address_space(3))) void*)l, 16, 0, 0);
}

// ---------------- DWT (Haar, level 1, last axis) ----------------
__global__ void dwt_kernel(const float* __restrict__ x, u16* __restrict__ x1,
                           u16* __restrict__ x2, int n) {
  int i = blockIdx.x * 256 + threadIdx.x;
  if (i >= n) return;
  float2 v = ((const float2*)x)[i];
  x1[i] = f2bf((v.x + v.y) * 0.70710678118f);
  x2[i] = f2bf((v.x - v.y) * 0.70710678118f);
}

// ---------------- weight transpose (Cout,Cin,3) -> bf16 (3,Cout,Cin) ----------------
__global__ void wtrans_kernel(const float* __restrict__ w, u16* __restrict__ wt,
                              int Cout, int Cin) {
  int e = blockIdx.x * 256 + threadIdx.x;
  if (e >= Cout * Cin * 3) return;
  int co = e / (Cin * 3);
  int r  = e - co * Cin * 3;
  int ci = r / 3;
  int t  = r - ci * 3;
  wt[((size_t)t * Cout + co) * Cin + ci] = f2bf(w[e]);
}

// ---------------- circular conv1d (k=3) as MFMA GEMM ----------------
// Chunked K-loop (chunk = ci-group x tap), Ws double-buffered via
// global_load_lds (swizzle on the global source), Zs reg-staged.
// Epilogue: LDS-transpose (reusing the Zs/Wb pool) -> fully-coalesced
// 16B/lane global stores for BOTH output layouts (osl==1 / osc==1).
__global__ __launch_bounds__(256, 3) void conv_mfma_kernel(
    const u16* __restrict__ Z, const u16* __restrict__ Wt,
    const float* __restrict__ bias, u16* __restrict__ out,
    int L, int Cin, int Cout, int osl, int osc, int relu) {
  __shared__ __align__(16) u16 smem[130 * 64 + 2 * 128 * 64];
  u16 (*Zs)[64] = (u16(*)[64])smem;                       // [130][64]
  u16 (*Wb)[128][64] = (u16(*)[128][64])(smem + 130 * 64); // [2][128][64]
  int l0 = blockIdx.x * 128, co0 = blockIdx.y * 128, b = blockIdx.z;
  int tid = threadIdx.x;
  int lane = tid & 63, w = tid >> 6, wr = w >> 1, wc = w & 1;
  int row16 = lane & 15, g4 = lane >> 4;
  f32x4 acc[4][4];
#pragma unroll
  for (int i = 0; i < 4; ++i)
#pragma unroll
    for (int j = 0; j < 4; ++j) acc[i][j] = (f32x4){0.f, 0.f, 0.f, 0.f};
  const u16* Zb = Z + (size_t)b * L * Cin;

  uint4 zr[5];
  auto zs_issue = [&](int c0) {
#pragma unroll
    for (int i = 0; i < 5; ++i) {
      int e = tid + i * 256;
      if (e < 130 * 8) {
        int r = e >> 3, c = e & 7;
        int gl = l0 + r - 1;
        if (gl < 0) gl += L; else if (gl >= L) gl -= L;
        zr[i] = *(const uint4*)(Zb + (size_t)gl * Cin + c0 + c * 8);
      }
    }
  };
  auto zs_write = [&]() {
#pragma unroll
    for (int i = 0; i < 5; ++i) {
      int e = tid + i * 256;
      if (e < 130 * 8) {
        int r = e >> 3, c = e & 7;
        *(uint4*)&Zs[r][(c ^ (r & 7)) * 8] = zr[i];
      }
    }
  };
  auto ws_issue = [&](int t, int c0, int buf) {
    const u16* Wg = Wt + ((size_t)t * Cout + co0) * Cin + c0;
    int c = lane & 7;
#pragma unroll
    for (int i = 0; i < 4; ++i) {
      int rw = (i * 4 + w) * 8 + (lane >> 3);
      gload16(Wg + (size_t)rw * Cin + ((c ^ (rw & 7)) * 8), &Wb[buf][(i * 4 + w) * 8][0]);
    }
  };

  int nchunk = (Cin >> 6) * 3;
  zs_issue(0);
  zs_write();
  ws_issue(0, 0, 0);
  __syncthreads();

  for (int k = 0; k < nchunk; ++k) {
    int t = k % 3;
    int c0 = (k / 3) << 6;
    int cur = k & 1;
    if (k + 1 < nchunk) ws_issue((k + 1) % 3, ((k + 1) / 3) << 6, cur ^ 1);
    bool bndry = (t == 2) && (c0 + 64 < Cin);
    if (bndry) zs_issue(c0 + 64);
#pragma unroll
    for (int ks = 0; ks < 2; ++ks) {
      int s = ks * 4 + g4;   // 16B slot index within row
      bf16x8 af[4], bfr[4];
#pragma unroll
      for (int mi = 0; mi < 4; ++mi) {
        int ra = wr * 64 + mi * 16 + row16 + t;
        af[mi] = *(const bf16x8*)&Zs[ra][(s ^ (ra & 7)) * 8];
      }
#pragma unroll
      for (int ni = 0; ni < 4; ++ni) {
        int rb = wc * 64 + ni * 16 + row16;
        bfr[ni] = *(const bf16x8*)&Wb[cur][rb][(s ^ (rb & 7)) * 8];
      }
#pragma unroll
      for (int mi = 0; mi < 4; ++mi)
#pragma unroll
        for (int ni = 0; ni < 4; ++ni)
          acc[mi][ni] = __builtin_amdgcn_mfma_f32_16x16x32_bf16(
              af[mi], bfr[ni], acc[mi][ni], 0, 0, 0);
    }
    __syncthreads();
    if (bndry) {
      zs_write();
      __syncthreads();
    }
  }

  // ---- coalesced epilogue: stage tile in LDS (row = strided dim) ----
  const int TP = 136;                 // padded row length (u16); 272B rotates banks by 4/row
  u16* tile = smem;                   // 128*136*2 = 34.8KB <= 49.9KB pool (safe: post-barrier)
  size_t ob = (size_t)b * L * Cout;
  int S, rowbase, colbase;
  if (osc == 1) { S = osl; rowbase = l0; colbase = co0; }
  else          { S = osc; rowbase = co0; colbase = l0; }
#pragma unroll
  for (int ni = 0; ni < 4; ++ni) {
    int c_loc = wc * 64 + ni * 16 + row16;
    float bz = bias[co0 + c_loc];
#pragma unroll
    for (int mi = 0; mi < 4; ++mi) {
#pragma unroll
      for (int r = 0; r < 4; ++r) {
        int l_loc = wr * 64 + mi * 16 + g4 * 4 + r;
        float v = acc[mi][ni][r] + bz;
        if (relu) v = fmaxf(v, 0.f);
        int row = (osc == 1) ? l_loc : c_loc;
        int col = (osc == 1) ? c_loc : l_loc;
        tile[row * TP + col] = f2bf(v);
      }
    }
  }
  __syncthreads();
  for (int e = tid; e < 128 * 16; e += 256) {
    int row = e >> 4, c8 = (e & 15) * 8;
    *(uint4*)(out + ob + (size_t)(rowbase + row) * S + colbase + c8) =
        *(const uint4*)&tile[row * TP + c8];
  }
}

// ---------------- fused cross attention, MFMA (unchanged) ----------------
__global__ __launch_bounds__(256, 4) void attn_mfma_kernel(
    const u16* __restrict__ qh, const u16* __restrict__ kh, const u16* __restrict__ vhT,
    const u16* __restrict__ ql, const u16* __restrict__ kl, const u16* __restrict__ vlT,
    u16* __restrict__ ctx) {
  __shared__ u16 Qs[64][72], Ks[64][72], Vts[64][72];
  __shared__ u16 Ps[64][72];
  __shared__ float rsl[2][2][32];
  int qt = blockIdx.x, h = blockIdx.y, bz = blockIdx.z;
  int b = bz >> 1, br = bz & 1;
  const u16* Q  = br ? ql  : qh;
  const u16* K  = br ? kh  : kl;
  const u16* Vt = br ? vlT : vhT;
  int tid = threadIdx.x;
  int lane = tid & 63, w = tid >> 6, wr = w >> 1, wc = w & 1;
  int row16 = lane & 15, g4 = lane >> 4, k8 = g4 * 8;
  int q0 = qt * 64;
  size_t baseQK = (size_t)b * FEA_ * DM_ + h * 64;
  size_t baseV  = (size_t)b * DM_ * FEA_ + (size_t)(h * 64) * FEA_;
  for (int e = tid; e < 64 * 8; e += 256) {
    int r = e >> 3, c = e & 7;
    *(uint4*)&Qs[r][c * 8] = *(const uint4*)(Q + baseQK + (size_t)(q0 + r) * DM_ + c * 8);
  }
  f32x4 oacc[2][2];
  float rsum[2][4];
#pragma unroll
  for (int i = 0; i < 2; ++i) {
#pragma unroll
    for (int j = 0; j < 2; ++j) oacc[i][j] = (f32x4){0.f, 0.f, 0.f, 0.f};
#pragma unroll
    for (int r = 0; r < 4; ++r) rsum[i][r] = 0.f;
  }
  for (int kt = 0; kt < 8; ++kt) {
    __syncthreads();
    for (int e = tid; e < 64 * 8; e += 256) {
      int r = e >> 3, c = e & 7;
      *(uint4*)&Ks[r][c * 8]  = *(const uint4*)(K + baseQK + (size_t)(kt * 64 + r) * DM_ + c * 8);
      *(uint4*)&Vts[r][c * 8] = *(const uint4*)(Vt + baseV + (size_t)r * FEA_ + kt * 64 + c * 8);
    }
    __syncthreads();
    f32x4 sacc[2][2];
#pragma unroll
    for (int i = 0; i < 2; ++i)
#pragma unroll
      for (int j = 0; j < 2; ++j) sacc[i][j] = (f32x4){0.f, 0.f, 0.f, 0.f};
#pragma unroll
    for (int ks = 0; ks < 2; ++ks) {
      int k0 = ks * 32 + k8;
      bf16x8 a0 = *(const bf16x8*)&Qs[wr * 32 + row16][k0];
      bf16x8 a1 = *(const bf16x8*)&Qs[wr * 32 + 16 + row16][k0];
      bf16x8 b0 = *(const bf16x8*)&Ks[wc * 32 + row16][k0];
      bf16x8 b1 = *(const bf16x8*)&Ks[wc * 32 + 16 + row16][k0];
      sacc[0][0] = __builtin_amdgcn_mfma_f32_16x16x32_bf16(a0, b0, sacc[0][0], 0, 0, 0);
      sacc[0][1] = __builtin_amdgcn_mfma_f32_16x16x32_bf16(a0, b1, sacc[0][1], 0, 0, 0);
      sacc[1][0] = __builtin_amdgcn_mfma_f32_16x16x32_bf16(a1, b0, sacc[1][0], 0, 0, 0);
      sacc[1][1] = __builtin_amdgcn_mfma_f32_16x16x32_bf16(a1, b1, sacc[1][1], 0, 0, 0);
    }
#pragma unroll
    for (int mi = 0; mi < 2; ++mi)
#pragma unroll
      for (int ni = 0; ni < 2; ++ni)
#pragma unroll
        for (int r = 0; r < 4; ++r) {
          float p = __expf(sacc[mi][ni][r] * 0.25f);
          rsum[mi][r] += p;
          Ps[wr * 32 + mi * 16 + g4 * 4 + r][wc * 32 + ni * 16 + row16] = f2bf(p);
        }
    __syncthreads();
#pragma unroll
    for (int ks = 0; ks < 2; ++ks) {
      int k0 = ks * 32 + k8;
      bf16x8 a0 = *(const bf16x8*)&Ps[wr * 32 + row16][k0];
      bf16x8 a1 = *(const bf16x8*)&Ps[wr * 32 + 16 + row16][k0];
      bf16x8 b0 = *(const bf16x8*)&Vts[wc * 32 + row16][k0];
      bf16x8 b1 = *(const bf16x8*)&Vts[wc * 32 + 16 + row16][k0];
      oacc[0][0] = __builtin_amdgcn_mfma_f32_16x16x32_bf16(a0, b0, oacc[0][0], 0, 0, 0);
      oacc[0][1] = __builtin_amdgcn_mfma_f32_16x16x32_bf16(a0, b1, oacc[0][1], 0, 0, 0);
      oacc[1][0] = __builtin_amdgcn_mfma_f32_16x16x32_bf16(a1, b0, oacc[1][0], 0, 0, 0);
      oacc[1][1] = __builtin_amdgcn_mfma_f32_16x16x32_bf16(a1, b1, oacc[1][1], 0, 0, 0);
    }
  }
#pragma unroll
  for (int mi = 0; mi < 2; ++mi)
#pragma unroll
    for (int r = 0; r < 4; ++r) {
#pragma unroll
      for (int m = 1; m < 16; m <<= 1) rsum[mi][r] += __shfl_xor(rsum[mi][r], m);
    }
  if (row16 == 0) {
#pragma unroll
    for (int mi = 0; mi < 2; ++mi)
#pragma unroll
      for (int r = 0; r < 4; ++r) rsl[wr][wc][mi * 16 + g4 * 4 + r] = rsum[mi][r];
  }
  __syncthreads();
#pragma unroll
  for (int mi = 0; mi < 2; ++mi)
#pragma unroll
    for (int ni = 0; ni < 2; ++ni)
#pragma unroll
      for (int r = 0; r < 4; ++r) {
        int qq = mi * 16 + g4 * 4 + r;
        float denom = rsl[wr][0][qq] + rsl[wr][1][qq];
        float o = oacc[mi][ni][r] / denom;
        Ps[wc * 32 + ni * 16 + row16][wr * 32 + qq] = f2bf(o);
      }
  __syncthreads();
  for (int e = tid; e < 64 * 8; e += 256) {
    int r = e >> 3, c = e & 7;
    size_t dst = ((size_t)b * DM_ + h * 64 + r) * (2 * FEA_) + br * 512 + q0 + c * 8;
    *(uint4*)(ctx + dst) = *(const uint4*)&Ps[r][c * 8];
  }
}

// ---------------- LayerNorm over last axis (+optional f32 residual out) ----------------
template <int RESID>
__global__ void ln_kernel(const u16* __restrict__ in, const float* __restrict__ g,
                          const float* __restrict__ beta, const float* __restrict__ resid,
                          void* __restrict__ outp, int C) {
  int row = blockIdx.x;
  int tid = threadIdx.x;
  const u16* p = in + (size_t)row * C;
  float s = 0.f, ss = 0.f;
  for (int c = tid; c < C; c += 256) {
    float v = bf2f(p[c]);
    s += v; ss += v * v;
  }
#pragma unroll
  for (int m = 1; m < 64; m <<= 1) { s += __shfl_xor(s, m); ss += __shfl_xor(ss, m); }
  __shared__ float red[2][4];
  int wid = tid >> 6, lane = tid & 63;
  if (lane == 0) { red[0][wid] = s; red[1][wid] = ss; }
  __syncthreads();
  s  = red[0][0] + red[0][1] + red[0][2] + red[0][3];
  ss = red[1][0] + red[1][1] + red[1][2] + red[1][3];
  float m  = s / C;
  float var = ss / C - m * m;
  float inv = rsqrtf(var + 1e-5f);
  for (int c = tid; c < C; c += 256) {
    float v = (bf2f(p[c]) - m) * inv * g[c] + beta[c];
    if (RESID) ((float*)outp)[(size_t)row * C + c] = v + resid[(size_t)row * C + c];
    else       ((u16*)outp)[(size_t)row * C + c]   = f2bf(v);
  }
}

extern "C" void kernel_launch(void* const* d_in, const int* in_sizes, int n_in,
                              void* d_out, int out_size, void* d_ws, size_t ws_size,
                              hipStream_t stream) {
  (void)in_sizes; (void)n_in; (void)out_size; (void)ws_size;
  const float* x      = (const float*)d_in[0];
  const float* Wq     = (const float*)d_in[1];
  const float* bq     = (const float*)d_in[2];
  const float* Wk     = (const float*)d_in[3];
  const float* bk     = (const float*)d_in[4];
  const float* Wv     = (const float*)d_in[5];
  const float* bv     = (const float*)d_in[6];
  const float* uns_w  = (const float*)d_in[7];
  const float* uns_b  = (const float*)d_in[8];
  const float* cv_w1  = (const float*)d_in[9];
  const float* cv_b1  = (const float*)d_in[10];
  const float* cv_w2  = (const float*)d_in[11];
  const float* cv_b2  = (const float*)d_in[12];
  const float* cv_g   = (const float*)d_in[13];
  const float* cv_beta= (const float*)d_in[14];
  const float* up_w1  = (const float*)d_in[15];
  const float* up_b1  = (const float*)d_in[16];
  const float* up_w2  = (const float*)d_in[17];
  const float* up_b2  = (const float*)d_in[18];
  const float* up_g   = (const float*)d_in[19];
  const float* up_beta= (const float*)d_in[20];

  // ---- workspace plan (peak 112 MiB of d_ws; d_out doubles as scratch) ----
  char* ws = (char*)d_ws;
  const size_t MB = 1ull << 20;
  u16* x1    = (u16*)(ws + 0);
  u16* x2    = (u16*)(ws + 8 * MB);
  u16* qhb   = (u16*)(ws + 16 * MB);
  u16* khb   = (u16*)(ws + 32 * MB);
  u16* vhb   = (u16*)(ws + 48 * MB);   // stored TRANSPOSED: [b][d][fea]
  u16* qlb   = (u16*)(ws + 64 * MB);
  u16* klb   = (u16*)(ws + 80 * MB);
  u16* vlb   = (u16*)(ws + 96 * MB);   // stored TRANSPOSED: [b][d][fea]
  u16* wt_proj = (u16*)d_out;
  u16* ctx   = (u16*)d_out;
  u16* wt_uns = (u16*)(ws + 0);
  u16* ctx2  = (u16*)(ws + 16 * MB);
  u16* wt_cv1 = (u16*)(ws + 32 * MB);
  u16* h1    = (u16*)(ws + 56 * MB);
  u16* wt_cv2 = (u16*)(ws + 32 * MB);
  u16* h2    = (u16*)(ws + 0);
  u16* ctx3  = (u16*)(ws + 8 * MB);
  u16* wt_up1 = (u16*)(ws + 16 * MB);
  u16* h3    = (u16*)(ws + 32 * MB);
  u16* wt_up2 = (u16*)(ws + 64 * MB);
  u16* h4    = (u16*)(ws + 16 * MB);

  dwt_kernel<<<(B_ * FEA_ * HALF_ + 255) / 256, 256, 0, stream>>>(x, x1, x2, B_ * FEA_ * HALF_);

  auto wtr = [&](const float* w, u16* wt, int Cout, int Cin) {
    wtrans_kernel<<<(Cout * Cin * 3 + 255) / 256, 256, 0, stream>>>(w, wt, Cout, Cin);
  };
  auto conv = [&](const u16* Z, const u16* wt, const float* bias, u16* out, int L,
                  int Cin, int Cout, int osl, int osc, int relu) {
    conv_mfma_kernel<<<dim3(L / 128, Cout / 128, B_), 256, 0, stream>>>(
        Z, wt, bias, out, L, Cin, Cout, osl, osc, relu);
  };

  // projections (shared weights across both DWT branches); V written transposed
  wtr(Wq, wt_proj, DM_, HALF_);
  conv(x1, wt_proj, bq, qhb, FEA_, HALF_, DM_, DM_, 1, 0);
  conv(x2, wt_proj, bq, qlb, FEA_, HALF_, DM_, DM_, 1, 0);
  wtr(Wk, wt_proj, DM_, HALF_);
  conv(x1, wt_proj, bk, khb, FEA_, HALF_, DM_, DM_, 1, 0);
  conv(x2, wt_proj, bk, klb, FEA_, HALF_, DM_, DM_, 1, 0);
  wtr(Wv, wt_proj, DM_, HALF_);
  conv(x1, wt_proj, bv, vhb, FEA_, HALF_, DM_, 1, FEA_, 0);
  conv(x2, wt_proj, bv, vlb, FEA_, HALF_, DM_, 1, FEA_, 0);

  attn_mfma_kernel<<<dim3(8, 16, 32), 256, 0, stream>>>(qhb, khb, vhb, qlb, klb, vlb, ctx);

  // unsqueeze conv: conv along d axis, channels 2F->F, transposed write -> ctx2[b][f][d]
  wtr(uns_w, wt_uns, FEA_, 2 * FEA_);
  conv(ctx, wt_uns, uns_b, ctx2, DM_, 2 * FEA_, FEA_, 1, DM_, 0);

  // Convlayer: D_MODEL -> D_FF -> HALF (conv along fea axis), then LN
  wtr(cv_w1, wt_cv1, DFF_, DM_);
  conv(ctx2, wt_cv1, cv_b1, h1, FEA_, DM_, DFF_, DFF_, 1, 1);
  wtr(cv_w2, wt_cv2, HALF_, DFF_);
  conv(h1, wt_cv2, cv_b2, h2, FEA_, DFF_, HALF_, HALF_, 1, 0);
  ln_kernel<0><<<B_ * FEA_, 256, 0, stream>>>(h2, cv_g, cv_beta, nullptr, ctx3, HALF_);

  // upsizeConvlayer: HALF -> D_FF -> D_MODEL, then LN + residual
  wtr(up_w1, wt_up1, DFF_, HALF_);
  conv(ctx3, wt_up1, up_b1, h3, FEA_, HALF_, DFF_, DFF_, 1, 1);
  wtr(up_w2, wt_up2, DM_, DFF_);
  conv(h3, wt_up2, up_b2, h4, FEA_, DFF_, DM_, DM_, 1, 0);
  ln_kernel<1><<<B_ * FEA_, 256, 0, stream>>>(h4, up_g, up_beta, x, d_out, DM_);
}

// Round 10
// 1028.793 us; speedup vs baseline: 1.1495x; 1.1153x over previous
//
#include <hip/hip_runtime.h>
#include <hip/hip_bf16.h>

#define B_    16
#define FEA_  512
#define DM_   1024
#define HALF_ 512
#define DFF_  2048

typedef unsigned short u16;
typedef __attribute__((ext_vector_type(8))) short bf16x8;
typedef __attribute__((ext_vector_type(4))) float f32x4;

__device__ __forceinline__ float bf2f(u16 u) {
  union { unsigned int i; float f; } v; v.i = ((unsigned int)u) << 16; return v.f;
}
__device__ __forceinline__ u16 f2bf(float f) {
  union { float f; unsigned int i; } v; v.f = f;
  unsigned int x = v.i;
  return (u16)((x + 0x7fffu + ((x >> 16) & 1u)) >> 16);
}
__device__ __forceinline__ void gload16(const u16* g, u16* l) {
  __builtin_amdgcn_global_load_lds(
      (const __attribute__((address_space(1))) void*)g,
      (__attribute__((address_space(3))) void*)l, 16, 0, 0);
}

// ---------------- DWT (Haar, level 1, last axis) ----------------
__global__ void dwt_kernel(const float* __restrict__ x, u16* __restrict__ x1,
                           u16* __restrict__ x2, int n) {
  int i = blockIdx.x * 256 + threadIdx.x;
  if (i >= n) return;
  float2 v = ((const float2*)x)[i];
  x1[i] = f2bf((v.x + v.y) * 0.70710678118f);
  x2[i] = f2bf((v.x - v.y) * 0.70710678118f);
}

// ---------------- weight transpose (Cout,Cin,3) -> bf16 (3,Cout,Cin) ----------------
__global__ void wtrans_kernel(const float* __restrict__ w, u16* __restrict__ wt,
                              int Cout, int Cin) {
  int e = blockIdx.x * 256 + threadIdx.x;
  if (e >= Cout * Cin * 3) return;
  int co = e / (Cin * 3);
  int r  = e - co * Cin * 3;
  int ci = r / 3;
  int t  = r - ci * 3;
  wt[((size_t)t * Cout + co) * Cin + ci] = f2bf(w[e]);
}

// ---------------- circular conv1d (k=3) as MFMA GEMM ----------------
// Chunked K-loop (chunk = ci-group x tap), Ws double-buffered via
// global_load_lds, Zs reg-staged. NO lambdas around staging state: zr[] and
// the precomputed zsrc/zdst pointers are plain locals with static indexing
// (lambda-by-ref capture made them scratch-allocated => ~145MB phantom HBM
// write traffic + barrier-serial scratch latency in rounds 7-9).
#define ZS_ISSUE(c0_)                                                        \
  {                                                                          \
    _Pragma("unroll") for (int i_ = 0; i_ < 4; ++i_)                         \
        zr[i_] = *(const uint4*)(zsrc[i_] + (c0_));                          \
    if (z4) zr[4] = *(const uint4*)(zsrc[4] + (c0_));                        \
  }
#define ZS_WRITE()                                                           \
  {                                                                          \
    _Pragma("unroll") for (int i_ = 0; i_ < 4; ++i_)                         \
        *(uint4*)zdst[i_] = zr[i_];                                          \
    if (z4) *(uint4*)zdst[4] = zr[4];                                        \
  }
#define WS_ISSUE(t_, c0_, buf_)                                              \
  {                                                                          \
    const u16* Wg_ = Wt + ((size_t)(t_) * Cout + co0) * Cin + (c0_);         \
    int c_ = lane & 7;                                                       \
    _Pragma("unroll") for (int i_ = 0; i_ < 4; ++i_) {                       \
      int rw_ = (i_ * 4 + w) * 8 + (lane >> 3);                              \
      gload16(Wg_ + (size_t)rw_ * Cin + ((c_ ^ (rw_ & 7)) * 8),              \
              &Wb[(buf_)][(i_ * 4 + w) * 8][0]);                             \
    }                                                                        \
  }

__global__ __launch_bounds__(256, 3) void conv_mfma_kernel(
    const u16* __restrict__ Z, const u16* __restrict__ Wt,
    const float* __restrict__ bias, u16* __restrict__ out,
    int L, int Cin, int Cout, int osl, int osc, int relu) {
  __shared__ __align__(16) u16 smem[130 * 64 + 2 * 128 * 64];
  u16 (*Zs)[64] = (u16(*)[64])smem;                        // [130][64]
  u16 (*Wb)[128][64] = (u16(*)[128][64])(smem + 130 * 64); // [2][128][64]
  int l0 = blockIdx.x * 128, co0 = blockIdx.y * 128, b = blockIdx.z;
  int tid = threadIdx.x;
  int lane = tid & 63, w = tid >> 6, wr = w >> 1, wc = w & 1;
  int row16 = lane & 15, g4 = lane >> 4;
  f32x4 acc[4][4];
#pragma unroll
  for (int i = 0; i < 4; ++i)
#pragma unroll
    for (int j = 0; j < 4; ++j) acc[i][j] = (f32x4){0.f, 0.f, 0.f, 0.f};
  const u16* Zb = Z + (size_t)b * L * Cin;

  // per-thread Z staging slots: element e = tid + i*256 (i=4 only for tid<16)
  uint4 zr[5];
  const u16* zsrc[5];
  u16* zdst[5];
  bool z4 = (tid < 16);
#pragma unroll
  for (int i = 0; i < 5; ++i) {
    int e = tid + i * 256;
    int r = e >> 3, c = e & 7;
    if (e >= 130 * 8) { r = 0; c = 0; }   // dummy (never stored: z4 guards i==4)
    int gl = l0 + r - 1;
    if (gl < 0) gl += L; else if (gl >= L) gl -= L;
    zsrc[i] = Zb + (size_t)gl * Cin + c * 8;
    zdst[i] = &Zs[r][(c ^ (r & 7)) * 8];
  }

  int nchunk = (Cin >> 6) * 3;
  ZS_ISSUE(0);
  ZS_WRITE();
  WS_ISSUE(0, 0, 0);
  __syncthreads();

  for (int k = 0; k < nchunk; ++k) {
    int t = k % 3;
    int c0 = (k / 3) << 6;
    int cur = k & 1;
    if (k + 1 < nchunk) WS_ISSUE((k + 1) % 3, ((k + 1) / 3) << 6, cur ^ 1);
    bool bndry = (t == 2) && (c0 + 64 < Cin);
    if (bndry) ZS_ISSUE(c0 + 64);
#pragma unroll
    for (int ks = 0; ks < 2; ++ks) {
      int s = ks * 4 + g4;   // 16B slot index within row
      bf16x8 af[4], bfr[4];
#pragma unroll
      for (int mi = 0; mi < 4; ++mi) {
        int ra = wr * 64 + mi * 16 + row16 + t;
        af[mi] = *(const bf16x8*)&Zs[ra][(s ^ (ra & 7)) * 8];
      }
#pragma unroll
      for (int ni = 0; ni < 4; ++ni) {
        int rb = wc * 64 + ni * 16 + row16;
        bfr[ni] = *(const bf16x8*)&Wb[cur][rb][(s ^ (rb & 7)) * 8];
      }
#pragma unroll
      for (int mi = 0; mi < 4; ++mi)
#pragma unroll
        for (int ni = 0; ni < 4; ++ni)
          acc[mi][ni] = __builtin_amdgcn_mfma_f32_16x16x32_bf16(
              af[mi], bfr[ni], acc[mi][ni], 0, 0, 0);
    }
    __syncthreads();
    if (bndry) {
      ZS_WRITE();
      __syncthreads();
    }
  }

  // ---- coalesced epilogue: stage tile in LDS (row = strided dim) ----
  const int TP = 136;                 // padded row length (u16)
  u16* tile = smem;                   // 34.8KB <= 49.4KB pool (post-barrier reuse)
  size_t ob = (size_t)b * L * Cout;
  int S, rowbase, colbase;
  if (osc == 1) { S = osl; rowbase = l0; colbase = co0; }
  else          { S = osc; rowbase = co0; colbase = l0; }
#pragma unroll
  for (int ni = 0; ni < 4; ++ni) {
    int c_loc = wc * 64 + ni * 16 + row16;
    float bz = bias[co0 + c_loc];
#pragma unroll
    for (int mi = 0; mi < 4; ++mi) {
#pragma unroll
      for (int r = 0; r < 4; ++r) {
        int l_loc = wr * 64 + mi * 16 + g4 * 4 + r;
        float v = acc[mi][ni][r] + bz;
        if (relu) v = fmaxf(v, 0.f);
        int row = (osc == 1) ? l_loc : c_loc;
        int col = (osc == 1) ? c_loc : l_loc;
        tile[row * TP + col] = f2bf(v);
      }
    }
  }
  __syncthreads();
  for (int e = tid; e < 128 * 16; e += 256) {
    int row = e >> 4, c8 = (e & 15) * 8;
    *(uint4*)(out + ob + (size_t)(rowbase + row) * S + colbase + c8) =
        *(const uint4*)&tile[row * TP + c8];
  }
}

// ---------------- fused cross attention, MFMA (unchanged) ----------------
__global__ __launch_bounds__(256, 4) void attn_mfma_kernel(
    const u16* __restrict__ qh, const u16* __restrict__ kh, const u16* __restrict__ vhT,
    const u16* __restrict__ ql, const u16* __restrict__ kl, const u16* __restrict__ vlT,
    u16* __restrict__ ctx) {
  __shared__ u16 Qs[64][72], Ks[64][72], Vts[64][72];
  __shared__ u16 Ps[64][72];
  __shared__ float rsl[2][2][32];
  int qt = blockIdx.x, h = blockIdx.y, bz = blockIdx.z;
  int b = bz >> 1, br = bz & 1;
  const u16* Q  = br ? ql  : qh;
  const u16* K  = br ? kh  : kl;
  const u16* Vt = br ? vlT : vhT;
  int tid = threadIdx.x;
  int lane = tid & 63, w = tid >> 6, wr = w >> 1, wc = w & 1;
  int row16 = lane & 15, g4 = lane >> 4, k8 = g4 * 8;
  int q0 = qt * 64;
  size_t baseQK = (size_t)b * FEA_ * DM_ + h * 64;
  size_t baseV  = (size_t)b * DM_ * FEA_ + (size_t)(h * 64) * FEA_;
  for (int e = tid; e < 64 * 8; e += 256) {
    int r = e >> 3, c = e & 7;
    *(uint4*)&Qs[r][c * 8] = *(const uint4*)(Q + baseQK + (size_t)(q0 + r) * DM_ + c * 8);
  }
  f32x4 oacc[2][2];
  float rsum[2][4];
#pragma unroll
  for (int i = 0; i < 2; ++i) {
#pragma unroll
    for (int j = 0; j < 2; ++j) oacc[i][j] = (f32x4){0.f, 0.f, 0.f, 0.f};
#pragma unroll
    for (int r = 0; r < 4; ++r) rsum[i][r] = 0.f;
  }
  for (int kt = 0; kt < 8; ++kt) {
    __syncthreads();
    for (int e = tid; e < 64 * 8; e += 256) {
      int r = e >> 3, c = e & 7;
      *(uint4*)&Ks[r][c * 8]  = *(const uint4*)(K + baseQK + (size_t)(kt * 64 + r) * DM_ + c * 8);
      *(uint4*)&Vts[r][c * 8] = *(const uint4*)(Vt + baseV + (size_t)r * FEA_ + kt * 64 + c * 8);
    }
    __syncthreads();
    f32x4 sacc[2][2];
#pragma unroll
    for (int i = 0; i < 2; ++i)
#pragma unroll
      for (int j = 0; j < 2; ++j) sacc[i][j] = (f32x4){0.f, 0.f, 0.f, 0.f};
#pragma unroll
    for (int ks = 0; ks < 2; ++ks) {
      int k0 = ks * 32 + k8;
      bf16x8 a0 = *(const bf16x8*)&Qs[wr * 32 + row16][k0];
      bf16x8 a1 = *(const bf16x8*)&Qs[wr * 32 + 16 + row16][k0];
      bf16x8 b0 = *(const bf16x8*)&Ks[wc * 32 + row16][k0];
      bf16x8 b1 = *(const bf16x8*)&Ks[wc * 32 + 16 + row16][k0];
      sacc[0][0] = __builtin_amdgcn_mfma_f32_16x16x32_bf16(a0, b0, sacc[0][0], 0, 0, 0);
      sacc[0][1] = __builtin_amdgcn_mfma_f32_16x16x32_bf16(a0, b1, sacc[0][1], 0, 0, 0);
      sacc[1][0] = __builtin_amdgcn_mfma_f32_16x16x32_bf16(a1, b0, sacc[1][0], 0, 0, 0);
      sacc[1][1] = __builtin_amdgcn_mfma_f32_16x16x32_bf16(a1, b1, sacc[1][1], 0, 0, 0);
    }
#pragma unroll
    for (int mi = 0; mi < 2; ++mi)
#pragma unroll
      for (int ni = 0; ni < 2; ++ni)
#pragma unroll
        for (int r = 0; r < 4; ++r) {
          float p = __expf(sacc[mi][ni][r] * 0.25f);
          rsum[mi][r] += p;
          Ps[wr * 32 + mi * 16 + g4 * 4 + r][wc * 32 + ni * 16 + row16] = f2bf(p);
        }
    __syncthreads();
#pragma unroll
    for (int ks = 0; ks < 2; ++ks) {
      int k0 = ks * 32 + k8;
      bf16x8 a0 = *(const bf16x8*)&Ps[wr * 32 + row16][k0];
      bf16x8 a1 = *(const bf16x8*)&Ps[wr * 32 + 16 + row16][k0];
      bf16x8 b0 = *(const bf16x8*)&Vts[wc * 32 + row16][k0];
      bf16x8 b1 = *(const bf16x8*)&Vts[wc * 32 + 16 + row16][k0];
      oacc[0][0] = __builtin_amdgcn_mfma_f32_16x16x32_bf16(a0, b0, oacc[0][0], 0, 0, 0);
      oacc[0][1] = __builtin_amdgcn_mfma_f32_16x16x32_bf16(a0, b1, oacc[0][1], 0, 0, 0);
      oacc[1][0] = __builtin_amdgcn_mfma_f32_16x16x32_bf16(a1, b0, oacc[1][0], 0, 0, 0);
      oacc[1][1] = __builtin_amdgcn_mfma_f32_16x16x32_bf16(a1, b1, oacc[1][1], 0, 0, 0);
    }
  }
#pragma unroll
  for (int mi = 0; mi < 2; ++mi)
#pragma unroll
    for (int r = 0; r < 4; ++r) {
#pragma unroll
      for (int m = 1; m < 16; m <<= 1) rsum[mi][r] += __shfl_xor(rsum[mi][r], m);
    }
  if (row16 == 0) {
#pragma unroll
    for (int mi = 0; mi < 2; ++mi)
#pragma unroll
      for (int r = 0; r < 4; ++r) rsl[wr][wc][mi * 16 + g4 * 4 + r] = rsum[mi][r];
  }
  __syncthreads();
#pragma unroll
  for (int mi = 0; mi < 2; ++mi)
#pragma unroll
    for (int ni = 0; ni < 2; ++ni)
#pragma unroll
      for (int r = 0; r < 4; ++r) {
        int qq = mi * 16 + g4 * 4 + r;
        float denom = rsl[wr][0][qq] + rsl[wr][1][qq];
        float o = oacc[mi][ni][r] / denom;
        Ps[wc * 32 + ni * 16 + row16][wr * 32 + qq] = f2bf(o);
      }
  __syncthreads();
  for (int e = tid; e < 64 * 8; e += 256) {
    int r = e >> 3, c = e & 7;
    size_t dst = ((size_t)b * DM_ + h * 64 + r) * (2 * FEA_) + br * 512 + q0 + c * 8;
    *(uint4*)(ctx + dst) = *(const uint4*)&Ps[r][c * 8];
  }
}

// ---------------- LayerNorm over last axis (+optional f32 residual out) ----------------
template <int RESID>
__global__ void ln_kernel(const u16* __restrict__ in, const float* __restrict__ g,
                          const float* __restrict__ beta, const float* __restrict__ resid,
                          void* __restrict__ outp, int C) {
  int row = blockIdx.x;
  int tid = threadIdx.x;
  const u16* p = in + (size_t)row * C;
  float s = 0.f, ss = 0.f;
  for (int c = tid; c < C; c += 256) {
    float v = bf2f(p[c]);
    s += v; ss += v * v;
  }
#pragma unroll
  for (int m = 1; m < 64; m <<= 1) { s += __shfl_xor(s, m); ss += __shfl_xor(ss, m); }
  __shared__ float red[2][4];
  int wid = tid >> 6, lane = tid & 63;
  if (lane == 0) { red[0][wid] = s; red[1][wid] = ss; }
  __syncthreads();
  s  = red[0][0] + red[0][1] + red[0][2] + red[0][3];
  ss = red[1][0] + red[1][1] + red[1][2] + red[1][3];
  float m  = s / C;
  float var = ss / C - m * m;
  float inv = rsqrtf(var + 1e-5f);
  for (int c = tid; c < C; c += 256) {
    float v = (bf2f(p[c]) - m) * inv * g[c] + beta[c];
    if (RESID) ((float*)outp)[(size_t)row * C + c] = v + resid[(size_t)row * C + c];
    else       ((u16*)outp)[(size_t)row * C + c]   = f2bf(v);
  }
}

extern "C" void kernel_launch(void* const* d_in, const int* in_sizes, int n_in,
                              void* d_out, int out_size, void* d_ws, size_t ws_size,
                              hipStream_t stream) {
  (void)in_sizes; (void)n_in; (void)out_size; (void)ws_size;
  const float* x      = (const float*)d_in[0];
  const float* Wq     = (const float*)d_in[1];
  const float* bq     = (const float*)d_in[2];
  const float* Wk     = (const float*)d_in[3];
  const float* bk     = (const float*)d_in[4];
  const float* Wv     = (const float*)d_in[5];
  const float* bv     = (const float*)d_in[6];
  const float* uns_w  = (const float*)d_in[7];
  const float* uns_b  = (const float*)d_in[8];
  const float* cv_w1  = (const float*)d_in[9];
  const float* cv_b1  = (const float*)d_in[10];
  const float* cv_w2  = (const float*)d_in[11];
  const float* cv_b2  = (const float*)d_in[12];
  const float* cv_g   = (const float*)d_in[13];
  const float* cv_beta= (const float*)d_in[14];
  const float* up_w1  = (const float*)d_in[15];
  const float* up_b1  = (const float*)d_in[16];
  const float* up_w2  = (const float*)d_in[17];
  const float* up_b2  = (const float*)d_in[18];
  const float* up_g   = (const float*)d_in[19];
  const float* up_beta= (const float*)d_in[20];

  // ---- workspace plan (peak 112 MiB of d_ws; d_out doubles as scratch) ----
  char* ws = (char*)d_ws;
  const size_t MB = 1ull << 20;
  u16* x1    = (u16*)(ws + 0);
  u16* x2    = (u16*)(ws + 8 * MB);
  u16* qhb   = (u16*)(ws + 16 * MB);
  u16* khb   = (u16*)(ws + 32 * MB);
  u16* vhb   = (u16*)(ws + 48 * MB);   // stored TRANSPOSED: [b][d][fea]
  u16* qlb   = (u16*)(ws + 64 * MB);
  u16* klb   = (u16*)(ws + 80 * MB);
  u16* vlb   = (u16*)(ws + 96 * MB);   // stored TRANSPOSED: [b][d][fea]
  u16* wt_proj = (u16*)d_out;
  u16* ctx   = (u16*)d_out;
  u16* wt_uns = (u16*)(ws + 0);
  u16* ctx2  = (u16*)(ws + 16 * MB);
  u16* wt_cv1 = (u16*)(ws + 32 * MB);
  u16* h1    = (u16*)(ws + 56 * MB);
  u16* wt_cv2 = (u16*)(ws + 32 * MB);
  u16* h2    = (u16*)(ws + 0);
  u16* ctx3  = (u16*)(ws + 8 * MB);
  u16* wt_up1 = (u16*)(ws + 16 * MB);
  u16* h3    = (u16*)(ws + 32 * MB);
  u16* wt_up2 = (u16*)(ws + 64 * MB);
  u16* h4    = (u16*)(ws + 16 * MB);

  dwt_kernel<<<(B_ * FEA_ * HALF_ + 255) / 256, 256, 0, stream>>>(x, x1, x2, B_ * FEA_ * HALF_);

  auto wtr = [&](const float* w, u16* wt, int Cout, int Cin) {
    wtrans_kernel<<<(Cout * Cin * 3 + 255) / 256, 256, 0, stream>>>(w, wt, Cout, Cin);
  };
  auto conv = [&](const u16* Z, const u16* wt, const float* bias, u16* out, int L,
                  int Cin, int Cout, int osl, int osc, int relu) {
    conv_mfma_kernel<<<dim3(L / 128, Cout / 128, B_), 256, 0, stream>>>(
        Z, wt, bias, out, L, Cin, Cout, osl, osc, relu);
  };

  // projections (shared weights across both DWT branches); V written transposed
  wtr(Wq, wt_proj, DM_, HALF_);
  conv(x1, wt_proj, bq, qhb, FEA_, HALF_, DM_, DM_, 1, 0);
  conv(x2, wt_proj, bq, qlb, FEA_, HALF_, DM_, DM_, 1, 0);
  wtr(Wk, wt_proj, DM_, HALF_);
  conv(x1, wt_proj, bk, khb, FEA_, HALF_, DM_, DM_, 1, 0);
  conv(x2, wt_proj, bk, klb, FEA_, HALF_, DM_, DM_, 1, 0);
  wtr(Wv, wt_proj, DM_, HALF_);
  conv(x1, wt_proj, bv, vhb, FEA_, HALF_, DM_, 1, FEA_, 0);
  conv(x2, wt_proj, bv, vlb, FEA_, HALF_, DM_, 1, FEA_, 0);

  attn_mfma_kernel<<<dim3(8, 16, 32), 256, 0, stream>>>(qhb, khb, vhb, qlb, klb, vlb, ctx);

  // unsqueeze conv: conv along d axis, channels 2F->F, transposed write -> ctx2[b][f][d]
  wtr(uns_w, wt_uns, FEA_, 2 * FEA_);
  conv(ctx, wt_uns, uns_b, ctx2, DM_, 2 * FEA_, FEA_, 1, DM_, 0);

  // Convlayer: D_MODEL -> D_FF -> HALF (conv along fea axis), then LN
  wtr(cv_w1, wt_cv1, DFF_, DM_);
  conv(ctx2, wt_cv1, cv_b1, h1, FEA_, DM_, DFF_, DFF_, 1, 1);
  wtr(cv_w2, wt_cv2, HALF_, DFF_);
  conv(h1, wt_cv2, cv_b2, h2, FEA_, DFF_, HALF_, HALF_, 1, 0);
  ln_kernel<0><<<B_ * FEA_, 256, 0, stream>>>(h2, cv_g, cv_beta, nullptr, ctx3, HALF_);

  // upsizeConvlayer: HALF -> D_FF -> D_MODEL, then LN + residual
  wtr(up_w1, wt_up1, DFF_, HALF_);
  conv(ctx3, wt_up1, up_b1, h3, FEA_, HALF_, DFF_, DFF_, 1, 1);
  wtr(up_w2, wt_up2, DM_, DFF_);
  conv(h3, wt_up2, up_b2, h4, FEA_, DFF_, DM_, DM_, 1, 0);
  ln_kernel<1><<<B_ * FEA_, 256, 0, stream>>>(h4, up_g, up_beta, x, d_out, DM_);
}

// Round 11
// 944.825 us; speedup vs baseline: 1.2517x; 1.0889x over previous
//
#include <hip/hip_runtime.h>
#include <hip/hip_bf16.h>

#define B_    16
#define FEA_  512
#define DM_   1024
#define HALF_ 512
#define DFF_  2048

typedef unsigned short u16;
typedef __attribute__((ext_vector_type(8))) short bf16x8;
typedef __attribute__((ext_vector_type(4))) float f32x4;

__device__ __forceinline__ float bf2f(u16 u) {
  union { unsigned int i; float f; } v; v.i = ((unsigned int)u) << 16; return v.f;
}
__device__ __forceinline__ u16 f2bf(float f) {
  union { float f; unsigned int i; } v; v.f = f;
  unsigned int x = v.i;
  return (u16)((x + 0x7fffu + ((x >> 16) & 1u)) >> 16);
}
__device__ __forceinline__ void gload16(const u16* g, u16* l) {
  __builtin_amdgcn_global_load_lds(
      (const __attribute__((address_space(1))) void*)g,
      (__attribute__((address_space(3))) void*)l, 16, 0, 0);
}

// ---------------- DWT (Haar, level 1, last axis) ----------------
__global__ void dwt_kernel(const float* __restrict__ x, u16* __restrict__ x1,
                           u16* __restrict__ x2, int n) {
  int i = blockIdx.x * 256 + threadIdx.x;
  if (i >= n) return;
  float2 v = ((const float2*)x)[i];
  x1[i] = f2bf((v.x + v.y) * 0.70710678118f);
  x2[i] = f2bf((v.x - v.y) * 0.70710678118f);
}

// ---------------- weight transpose (Cout,Cin,3) -> bf16 (3,Cout,Cin) ----------------
__global__ void wtrans_kernel(const float* __restrict__ w, u16* __restrict__ wt,
                              int Cout, int Cin) {
  int e = blockIdx.x * 256 + threadIdx.x;
  if (e >= Cout * Cin * 3) return;
  int co = e / (Cin * 3);
  int r  = e - co * Cin * 3;
  int ci = r / 3;
  int t  = r - ci * 3;
  wt[((size_t)t * Cout + co) * Cin + ci] = f2bf(w[e]);
}

// ---------------- circular conv1d (k=3) as MFMA GEMM ----------------
// Chunked K-loop (chunk = ci-group x tap). Ws double-buffered via
// global_load_lds (zero VGPR cost, swizzle on the global source). Zs staged
// IMMEDIATELY (load->ds_write, transient regs only) at ci-group boundaries:
// the round-7..10 issue-early/write-late split kept 40 VGPRs of addressable
// array state that the compiler put in scratch -> ~70-300MB phantom HBM
// traffic per conv (round-6 control: no split => WRITE == exact output).
#define ZS_STAGE(c0_)                                                        \
  {                                                                          \
    _Pragma("unroll") for (int i_ = 0; i_ < 5; ++i_) {                       \
      int e_ = tid + i_ * 256;                                               \
      if (e_ < 130 * 8) {                                                    \
        int r_ = e_ >> 3, c_ = e_ & 7;                                       \
        int gl_ = l0 + r_ - 1;                                               \
        if (gl_ < 0) gl_ += L; else if (gl_ >= L) gl_ -= L;                  \
        *(uint4*)&Zs[r_][(c_ ^ (r_ & 7)) * 8] =                              \
            *(const uint4*)(Zb + (size_t)gl_ * Cin + (c0_) + c_ * 8);        \
      }                                                                      \
    }                                                                        \
  }
#define WS_ISSUE(t_, c0_, buf_)                                              \
  {                                                                          \
    const u16* Wg_ = Wt + ((size_t)(t_) * Cout + co0) * Cin + (c0_);         \
    int c_ = lane & 7;                                                       \
    _Pragma("unroll") for (int i_ = 0; i_ < 4; ++i_) {                       \
      int rw_ = (i_ * 4 + w) * 8 + (lane >> 3);                              \
      gload16(Wg_ + (size_t)rw_ * Cin + ((c_ ^ (rw_ & 7)) * 8),              \
              &Wb[(buf_)][(i_ * 4 + w) * 8][0]);                             \
    }                                                                        \
  }

__global__ __launch_bounds__(256, 3) void conv_mfma_kernel(
    const u16* __restrict__ Z, const u16* __restrict__ Wt,
    const float* __restrict__ bias, u16* __restrict__ out,
    int L, int Cin, int Cout, int osl, int osc, int relu) {
  __shared__ __align__(16) u16 smem[130 * 64 + 2 * 128 * 64];
  u16 (*Zs)[64] = (u16(*)[64])smem;                        // [130][64]
  u16 (*Wb)[128][64] = (u16(*)[128][64])(smem + 130 * 64); // [2][128][64]
  int l0 = blockIdx.x * 128, co0 = blockIdx.y * 128, b = blockIdx.z;
  int tid = threadIdx.x;
  int lane = tid & 63, w = tid >> 6, wr = w >> 1, wc = w & 1;
  int row16 = lane & 15, g4 = lane >> 4;
  f32x4 acc[4][4];
#pragma unroll
  for (int i = 0; i < 4; ++i)
#pragma unroll
    for (int j = 0; j < 4; ++j) acc[i][j] = (f32x4){0.f, 0.f, 0.f, 0.f};
  const u16* Zb = Z + (size_t)b * L * Cin;

  int nchunk = (Cin >> 6) * 3;
  ZS_STAGE(0);
  WS_ISSUE(0, 0, 0);
  __syncthreads();

  for (int k = 0; k < nchunk; ++k) {
    int t = k % 3;
    int c0 = (k / 3) << 6;
    int cur = k & 1;
    if (k + 1 < nchunk) WS_ISSUE((k + 1) % 3, ((k + 1) / 3) << 6, cur ^ 1);
#pragma unroll
    for (int ks = 0; ks < 2; ++ks) {
      int s = ks * 4 + g4;   // 16B slot index within row
      bf16x8 af[4], bfr[4];
#pragma unroll
      for (int mi = 0; mi < 4; ++mi) {
        int ra = wr * 64 + mi * 16 + row16 + t;
        af[mi] = *(const bf16x8*)&Zs[ra][(s ^ (ra & 7)) * 8];
      }
#pragma unroll
      for (int ni = 0; ni < 4; ++ni) {
        int rb = wc * 64 + ni * 16 + row16;
        bfr[ni] = *(const bf16x8*)&Wb[cur][rb][(s ^ (rb & 7)) * 8];
      }
#pragma unroll
      for (int mi = 0; mi < 4; ++mi)
#pragma unroll
        for (int ni = 0; ni < 4; ++ni)
          acc[mi][ni] = __builtin_amdgcn_mfma_f32_16x16x32_bf16(
              af[mi], bfr[ni], acc[mi][ni], 0, 0, 0);
    }
    __syncthreads();   // drains next-chunk gload_lds; publishes compute done
    if ((t == 2) && (c0 + 64 < Cin)) {
      ZS_STAGE(c0 + 64);
      __syncthreads();
    }
  }

  // ---- coalesced epilogue: stage tile in LDS (row = strided dim) ----
  const int TP = 136;                 // padded row length (u16)
  u16* tile = smem;                   // 34.8KB <= 49.4KB pool (post-barrier reuse)
  size_t ob = (size_t)b * L * Cout;
  int S, rowbase, colbase;
  if (osc == 1) { S = osl; rowbase = l0; colbase = co0; }
  else          { S = osc; rowbase = co0; colbase = l0; }
#pragma unroll
  for (int ni = 0; ni < 4; ++ni) {
    int c_loc = wc * 64 + ni * 16 + row16;
    float bz = bias[co0 + c_loc];
#pragma unroll
    for (int mi = 0; mi < 4; ++mi) {
#pragma unroll
      for (int r = 0; r < 4; ++r) {
        int l_loc = wr * 64 + mi * 16 + g4 * 4 + r;
        float v = acc[mi][ni][r] + bz;
        if (relu) v = fmaxf(v, 0.f);
        int row = (osc == 1) ? l_loc : c_loc;
        int col = (osc == 1) ? c_loc : l_loc;
        tile[row * TP + col] = f2bf(v);
      }
    }
  }
  __syncthreads();
  for (int e = tid; e < 128 * 16; e += 256) {
    int row = e >> 4, c8 = (e & 15) * 8;
    *(uint4*)(out + ob + (size_t)(rowbase + row) * S + colbase + c8) =
        *(const uint4*)&tile[row * TP + c8];
  }
}

// ---------------- fused cross attention, MFMA (unchanged) ----------------
__global__ __launch_bounds__(256, 4) void attn_mfma_kernel(
    const u16* __restrict__ qh, const u16* __restrict__ kh, const u16* __restrict__ vhT,
    const u16* __restrict__ ql, const u16* __restrict__ kl, const u16* __restrict__ vlT,
    u16* __restrict__ ctx) {
  __shared__ u16 Qs[64][72], Ks[64][72], Vts[64][72];
  __shared__ u16 Ps[64][72];
  __shared__ float rsl[2][2][32];
  int qt = blockIdx.x, h = blockIdx.y, bz = blockIdx.z;
  int b = bz >> 1, br = bz & 1;
  const u16* Q  = br ? ql  : qh;
  const u16* K  = br ? kh  : kl;
  const u16* Vt = br ? vlT : vhT;
  int tid = threadIdx.x;
  int lane = tid & 63, w = tid >> 6, wr = w >> 1, wc = w & 1;
  int row16 = lane & 15, g4 = lane >> 4, k8 = g4 * 8;
  int q0 = qt * 64;
  size_t baseQK = (size_t)b * FEA_ * DM_ + h * 64;
  size_t baseV  = (size_t)b * DM_ * FEA_ + (size_t)(h * 64) * FEA_;
  for (int e = tid; e < 64 * 8; e += 256) {
    int r = e >> 3, c = e & 7;
    *(uint4*)&Qs[r][c * 8] = *(const uint4*)(Q + baseQK + (size_t)(q0 + r) * DM_ + c * 8);
  }
  f32x4 oacc[2][2];
  float rsum[2][4];
#pragma unroll
  for (int i = 0; i < 2; ++i) {
#pragma unroll
    for (int j = 0; j < 2; ++j) oacc[i][j] = (f32x4){0.f, 0.f, 0.f, 0.f};
#pragma unroll
    for (int r = 0; r < 4; ++r) rsum[i][r] = 0.f;
  }
  for (int kt = 0; kt < 8; ++kt) {
    __syncthreads();
    for (int e = tid; e < 64 * 8; e += 256) {
      int r = e >> 3, c = e & 7;
      *(uint4*)&Ks[r][c * 8]  = *(const uint4*)(K + baseQK + (size_t)(kt * 64 + r) * DM_ + c * 8);
      *(uint4*)&Vts[r][c * 8] = *(const uint4*)(Vt + baseV + (size_t)r * FEA_ + kt * 64 + c * 8);
    }
    __syncthreads();
    f32x4 sacc[2][2];
#pragma unroll
    for (int i = 0; i < 2; ++i)
#pragma unroll
      for (int j = 0; j < 2; ++j) sacc[i][j] = (f32x4){0.f, 0.f, 0.f, 0.f};
#pragma unroll
    for (int ks = 0; ks < 2; ++ks) {
      int k0 = ks * 32 + k8;
      bf16x8 a0 = *(const bf16x8*)&Qs[wr * 32 + row16][k0];
      bf16x8 a1 = *(const bf16x8*)&Qs[wr * 32 + 16 + row16][k0];
      bf16x8 b0 = *(const bf16x8*)&Ks[wc * 32 + row16][k0];
      bf16x8 b1 = *(const bf16x8*)&Ks[wc * 32 + 16 + row16][k0];
      sacc[0][0] = __builtin_amdgcn_mfma_f32_16x16x32_bf16(a0, b0, sacc[0][0], 0, 0, 0);
      sacc[0][1] = __builtin_amdgcn_mfma_f32_16x16x32_bf16(a0, b1, sacc[0][1], 0, 0, 0);
      sacc[1][0] = __builtin_amdgcn_mfma_f32_16x16x32_bf16(a1, b0, sacc[1][0], 0, 0, 0);
      sacc[1][1] = __builtin_amdgcn_mfma_f32_16x16x32_bf16(a1, b1, sacc[1][1], 0, 0, 0);
    }
#pragma unroll
    for (int mi = 0; mi < 2; ++mi)
#pragma unroll
      for (int ni = 0; ni < 2; ++ni)
#pragma unroll
        for (int r = 0; r < 4; ++r) {
          float p = __expf(sacc[mi][ni][r] * 0.25f);
          rsum[mi][r] += p;
          Ps[wr * 32 + mi * 16 + g4 * 4 + r][wc * 32 + ni * 16 + row16] = f2bf(p);
        }
    __syncthreads();
#pragma unroll
    for (int ks = 0; ks < 2; ++ks) {
      int k0 = ks * 32 + k8;
      bf16x8 a0 = *(const bf16x8*)&Ps[wr * 32 + row16][k0];
      bf16x8 a1 = *(const bf16x8*)&Ps[wr * 32 + 16 + row16][k0];
      bf16x8 b0 = *(const bf16x8*)&Vts[wc * 32 + row16][k0];
      bf16x8 b1 = *(const bf16x8*)&Vts[wc * 32 + 16 + row16][k0];
      oacc[0][0] = __builtin_amdgcn_mfma_f32_16x16x32_bf16(a0, b0, oacc[0][0], 0, 0, 0);
      oacc[0][1] = __builtin_amdgcn_mfma_f32_16x16x32_bf16(a0, b1, oacc[0][1], 0, 0, 0);
      oacc[1][0] = __builtin_amdgcn_mfma_f32_16x16x32_bf16(a1, b0, oacc[1][0], 0, 0, 0);
      oacc[1][1] = __builtin_amdgcn_mfma_f32_16x16x32_bf16(a1, b1, oacc[1][1], 0, 0, 0);
    }
  }
#pragma unroll
  for (int mi = 0; mi < 2; ++mi)
#pragma unroll
    for (int r = 0; r < 4; ++r) {
#pragma unroll
      for (int m = 1; m < 16; m <<= 1) rsum[mi][r] += __shfl_xor(rsum[mi][r], m);
    }
  if (row16 == 0) {
#pragma unroll
    for (int mi = 0; mi < 2; ++mi)
#pragma unroll
      for (int r = 0; r < 4; ++r) rsl[wr][wc][mi * 16 + g4 * 4 + r] = rsum[mi][r];
  }
  __syncthreads();
#pragma unroll
  for (int mi = 0; mi < 2; ++mi)
#pragma unroll
    for (int ni = 0; ni < 2; ++ni)
#pragma unroll
      for (int r = 0; r < 4; ++r) {
        int qq = mi * 16 + g4 * 4 + r;
        float denom = rsl[wr][0][qq] + rsl[wr][1][qq];
        float o = oacc[mi][ni][r] / denom;
        Ps[wc * 32 + ni * 16 + row16][wr * 32 + qq] = f2bf(o);
      }
  __syncthreads();
  for (int e = tid; e < 64 * 8; e += 256) {
    int r = e >> 3, c = e & 7;
    size_t dst = ((size_t)b * DM_ + h * 64 + r) * (2 * FEA_) + br * 512 + q0 + c * 8;
    *(uint4*)(ctx + dst) = *(const uint4*)&Ps[r][c * 8];
  }
}

// ---------------- LayerNorm over last axis (+optional f32 residual out) ----------------
template <int RESID>
__global__ void ln_kernel(const u16* __restrict__ in, const float* __restrict__ g,
                          const float* __restrict__ beta, const float* __restrict__ resid,
                          void* __restrict__ outp, int C) {
  int row = blockIdx.x;
  int tid = threadIdx.x;
  const u16* p = in + (size_t)row * C;
  float s = 0.f, ss = 0.f;
  for (int c = tid; c < C; c += 256) {
    float v = bf2f(p[c]);
    s += v; ss += v * v;
  }
#pragma unroll
  for (int m = 1; m < 64; m <<= 1) { s += __shfl_xor(s, m); ss += __shfl_xor(ss, m); }
  __shared__ float red[2][4];
  int wid = tid >> 6, lane = tid & 63;
  if (lane == 0) { red[0][wid] = s; red[1][wid] = ss; }
  __syncthreads();
  s  = red[0][0] + red[0][1] + red[0][2] + red[0][3];
  ss = red[1][0] + red[1][1] + red[1][2] + red[1][3];
  float m  = s / C;
  float var = ss / C - m * m;
  float inv = rsqrtf(var + 1e-5f);
  for (int c = tid; c < C; c += 256) {
    float v = (bf2f(p[c]) - m) * inv * g[c] + beta[c];
    if (RESID) ((float*)outp)[(size_t)row * C + c] = v + resid[(size_t)row * C + c];
    else       ((u16*)outp)[(size_t)row * C + c]   = f2bf(v);
  }
}

extern "C" void kernel_launch(void* const* d_in, const int* in_sizes, int n_in,
                              void* d_out, int out_size, void* d_ws, size_t ws_size,
                              hipStream_t stream) {
  (void)in_sizes; (void)n_in; (void)out_size; (void)ws_size;
  const float* x      = (const float*)d_in[0];
  const float* Wq     = (const float*)d_in[1];
  const float* bq     = (const float*)d_in[2];
  const float* Wk     = (const float*)d_in[3];
  const float* bk     = (const float*)d_in[4];
  const float* Wv     = (const float*)d_in[5];
  const float* bv     = (const float*)d_in[6];
  const float* uns_w  = (const float*)d_in[7];
  const float* uns_b  = (const float*)d_in[8];
  const float* cv_w1  = (const float*)d_in[9];
  const float* cv_b1  = (const float*)d_in[10];
  const float* cv_w2  = (const float*)d_in[11];
  const float* cv_b2  = (const float*)d_in[12];
  const float* cv_g   = (const float*)d_in[13];
  const float* cv_beta= (const float*)d_in[14];
  const float* up_w1  = (const float*)d_in[15];
  const float* up_b1  = (const float*)d_in[16];
  const float* up_w2  = (const float*)d_in[17];
  const float* up_b2  = (const float*)d_in[18];
  const float* up_g   = (const float*)d_in[19];
  const float* up_beta= (const float*)d_in[20];

  // ---- workspace plan (peak 112 MiB of d_ws; d_out doubles as scratch) ----
  char* ws = (char*)d_ws;
  const size_t MB = 1ull << 20;
  u16* x1    = (u16*)(ws + 0);
  u16* x2    = (u16*)(ws + 8 * MB);
  u16* qhb   = (u16*)(ws + 16 * MB);
  u16* khb   = (u16*)(ws + 32 * MB);
  u16* vhb   = (u16*)(ws + 48 * MB);   // stored TRANSPOSED: [b][d][fea]
  u16* qlb   = (u16*)(ws + 64 * MB);
  u16* klb   = (u16*)(ws + 80 * MB);
  u16* vlb   = (u16*)(ws + 96 * MB);   // stored TRANSPOSED: [b][d][fea]
  u16* wt_proj = (u16*)d_out;
  u16* ctx   = (u16*)d_out;
  u16* wt_uns = (u16*)(ws + 0);
  u16* ctx2  = (u16*)(ws + 16 * MB);
  u16* wt_cv1 = (u16*)(ws + 32 * MB);
  u16* h1    = (u16*)(ws + 56 * MB);
  u16* wt_cv2 = (u16*)(ws + 32 * MB);
  u16* h2    = (u16*)(ws + 0);
  u16* ctx3  = (u16*)(ws + 8 * MB);
  u16* wt_up1 = (u16*)(ws + 16 * MB);
  u16* h3    = (u16*)(ws + 32 * MB);
  u16* wt_up2 = (u16*)(ws + 64 * MB);
  u16* h4    = (u16*)(ws + 16 * MB);

  dwt_kernel<<<(B_ * FEA_ * HALF_ + 255) / 256, 256, 0, stream>>>(x, x1, x2, B_ * FEA_ * HALF_);

  auto wtr = [&](const float* w, u16* wt, int Cout, int Cin) {
    wtrans_kernel<<<(Cout * Cin * 3 + 255) / 256, 256, 0, stream>>>(w, wt, Cout, Cin);
  };
  auto conv = [&](const u16* Z, const u16* wt, const float* bias, u16* out, int L,
                  int Cin, int Cout, int osl, int osc, int relu) {
    conv_mfma_kernel<<<dim3(L / 128, Cout / 128, B_), 256, 0, stream>>>(
        Z, wt, bias, out, L, Cin, Cout, osl, osc, relu);
  };

  // projections (shared weights across both DWT branches); V written transposed
  wtr(Wq, wt_proj, DM_, HALF_);
  conv(x1, wt_proj, bq, qhb, FEA_, HALF_, DM_, DM_, 1, 0);
  conv(x2, wt_proj, bq, qlb, FEA_, HALF_, DM_, DM_, 1, 0);
  wtr(Wk, wt_proj, DM_, HALF_);
  conv(x1, wt_proj, bk, khb, FEA_, HALF_, DM_, DM_, 1, 0);
  conv(x2, wt_proj, bk, klb, FEA_, HALF_, DM_, DM_, 1, 0);
  wtr(Wv, wt_proj, DM_, HALF_);
  conv(x1, wt_proj, bv, vhb, FEA_, HALF_, DM_, 1, FEA_, 0);
  conv(x2, wt_proj, bv, vlb, FEA_, HALF_, DM_, 1, FEA_, 0);

  attn_mfma_kernel<<<dim3(8, 16, 32), 256, 0, stream>>>(qhb, khb, vhb, qlb, klb, vlb, ctx);

  // unsqueeze conv: conv along d axis, channels 2F->F, transposed write -> ctx2[b][f][d]
  wtr(uns_w, wt_uns, FEA_, 2 * FEA_);
  conv(ctx, wt_uns, uns_b, ctx2, DM_, 2 * FEA_, FEA_, 1, DM_, 0);

  // Convlayer: D_MODEL -> D_FF -> HALF (conv along fea axis), then LN
  wtr(cv_w1, wt_cv1, DFF_, DM_);
  conv(ctx2, wt_cv1, cv_b1, h1, FEA_, DM_, DFF_, DFF_, 1, 1);
  wtr(cv_w2, wt_cv2, HALF_, DFF_);
  conv(h1, wt_cv2, cv_b2, h2, FEA_, DFF_, HALF_, HALF_, 1, 0);
  ln_kernel<0><<<B_ * FEA_, 256, 0, stream>>>(h2, cv_g, cv_beta, nullptr, ctx3, HALF_);

  // upsizeConvlayer: HALF -> D_FF -> D_MODEL, then LN + residual
  wtr(up_w1, wt_up1, DFF_, HALF_);
  conv(ctx3, wt_up1, up_b1, h3, FEA_, HALF_, DFF_, DFF_, 1, 1);
  wtr(up_w2, wt_up2, DM_, DFF_);
  conv(h3, wt_up2, up_b2, h4, FEA_, DFF_, DM_, DM_, 1, 0);
  ln_kernel<1><<<B_ * FEA_, 256, 0, stream>>>(h4, up_g, up_beta, x, d_out, DM_);
}

// Round 12
// 748.562 us; speedup vs baseline: 1.5799x; 1.2622x over previous
//
#include <hip/hip_runtime.h>
#include <hip/hip_bf16.h>

#define B_    16
#define FEA_  512
#define DM_   1024
#define HALF_ 512
#define DFF_  2048

typedef unsigned short u16;
typedef __attribute__((ext_vector_type(8))) short bf16x8;
typedef __attribute__((ext_vector_type(4))) float f32x4;

__device__ __forceinline__ float bf2f(u16 u) {
  union { unsigned int i; float f; } v; v.i = ((unsigned int)u) << 16; return v.f;
}
__device__ __forceinline__ u16 f2bf(float f) {
  union { float f; unsigned int i; } v; v.f = f;
  unsigned int x = v.i;
  return (u16)((x + 0x7fffu + ((x >> 16) & 1u)) >> 16);
}
__device__ __forceinline__ void gload16(const u16* g, u16* l) {
  __builtin_amdgcn_global_load_lds(
      (const __attribute__((address_space(1))) void*)g,
      (__attribute__((address_space(3))) void*)l, 16, 0, 0);
}

// ---------------- DWT (Haar, level 1, last axis) ----------------
__global__ void dwt_kernel(const float* __restrict__ x, u16* __restrict__ x1,
                           u16* __restrict__ x2, int n) {
  int i = blockIdx.x * 256 + threadIdx.x;
  if (i >= n) return;
  float2 v = ((const float2*)x)[i];
  x1[i] = f2bf((v.x + v.y) * 0.70710678118f);
  x2[i] = f2bf((v.x - v.y) * 0.70710678118f);
}

// ---------------- weight transpose (Cout,Cin,3) -> bf16 (3,Cout,Cin) ----------------
__global__ void wtrans_kernel(const float* __restrict__ w, u16* __restrict__ wt,
                              int Cout, int Cin) {
  int e = blockIdx.x * 256 + threadIdx.x;
  if (e >= Cout * Cin * 3) return;
  int co = e / (Cin * 3);
  int r  = e - co * Cin * 3;
  int ci = r / 3;
  int t  = r - ci * 3;
  wt[((size_t)t * Cout + co) * Cin + ci] = f2bf(w[e]);
}

// ---------------- circular conv1d (k=3) as MFMA GEMM ----------------
// Counted-vmcnt pipelined K-loop (chunk = ci-group x tap): chunk k reads
// Wb[k%3]; W(k+2) issued at END of chunk k (3 buffers, 2-deep). Per-chunk
// wait = s_waitcnt vmcnt(4) + raw s_barrier (weights never drain to 0).
// FIFO at chunk k's wait: [W(k), Z?, W(k+1)] -> vmcnt(4) retires W(k)+Z.
// Z staged via global_load_lds too (source-swizzled, dest lane-linear),
// issued at ci-group boundary after a barrier, BEFORE W(k+2).
#define ZS_GLOAD(c0_)                                                        \
  {                                                                          \
    _Pragma("unroll") for (int i_ = 0; i_ < 5; ++i_) {                       \
      int e_ = tid + i_ * 256;                                               \
      if (e_ < 130 * 8) {                                                    \
        int r_ = e_ >> 3, c_ = e_ & 7;                                       \
        int gl_ = l0 + r_ - 1;                                               \
        if (gl_ < 0) gl_ += L; else if (gl_ >= L) gl_ -= L;                  \
        gload16(Zb + (size_t)gl_ * Cin + (c0_) + ((c_ ^ (r_ & 7)) * 8),      \
                smem + ((size_t)(i_ * 256 + (tid & 192)) * 8));              \
      }                                                                      \
    }                                                                        \
  }
#define WS_ISSUE(t_, c0_, buf_)                                              \
  {                                                                          \
    const u16* Wg_ = Wt + ((size_t)(t_) * Cout + co0) * Cin + (c0_);         \
    int c_ = lane & 7;                                                       \
    _Pragma("unroll") for (int i_ = 0; i_ < 4; ++i_) {                       \
      int rw_ = (i_ * 4 + w) * 8 + (lane >> 3);                              \
      gload16(Wg_ + (size_t)rw_ * Cin + ((c_ ^ (rw_ & 7)) * 8),              \
              &Wb[(buf_)][(i_ * 4 + w) * 8][0]);                             \
    }                                                                        \
  }

__global__ __launch_bounds__(256, 2) void conv_mfma_kernel(
    const u16* __restrict__ Z, const u16* __restrict__ Wt,
    const float* __restrict__ bias, u16* __restrict__ out,
    int L, int Cin, int Cout, int osl, int osc, int relu) {
  __shared__ __align__(16) u16 smem[130 * 64 + 3 * 128 * 64];
  u16 (*Zs)[64] = (u16(*)[64])smem;                        // [130][64]
  u16 (*Wb)[128][64] = (u16(*)[128][64])(smem + 130 * 64); // [3][128][64]
  int l0 = blockIdx.x * 128, co0 = blockIdx.y * 128, b = blockIdx.z;
  int tid = threadIdx.x;
  int lane = tid & 63, w = tid >> 6, wr = w >> 1, wc = w & 1;
  int row16 = lane & 15, g4 = lane >> 4;
  f32x4 acc[4][4];
#pragma unroll
  for (int i = 0; i < 4; ++i)
#pragma unroll
    for (int j = 0; j < 4; ++j) acc[i][j] = (f32x4){0.f, 0.f, 0.f, 0.f};
  const u16* Zb = Z + (size_t)b * L * Cin;

  int nchunk = (Cin >> 6) * 3;
  ZS_GLOAD(0);
  WS_ISSUE(0, 0, 0);
  WS_ISSUE(1, 0, 1);

  for (int k = 0; k < nchunk; ++k) {
    int t = k % 3;
    int c0 = (k / 3) << 6;
    int cur = k % 3;   // buffer index == k%3 (3-buffer rotation)
    // wait for own W(k) (+ Z of this group) to land, then converge
    if (k + 1 < nchunk) asm volatile("s_waitcnt vmcnt(4)" ::: "memory");
    else                asm volatile("s_waitcnt vmcnt(0)" ::: "memory");
    __builtin_amdgcn_s_barrier();
#pragma unroll
    for (int ks = 0; ks < 2; ++ks) {
      int s = ks * 4 + g4;   // 16B slot index within row
      bf16x8 af[4], bfr[4];
#pragma unroll
      for (int mi = 0; mi < 4; ++mi) {
        int ra = wr * 64 + mi * 16 + row16 + t;
        af[mi] = *(const bf16x8*)&Zs[ra][(s ^ (ra & 7)) * 8];
      }
#pragma unroll
      for (int ni = 0; ni < 4; ++ni) {
        int rb = wc * 64 + ni * 16 + row16;
        bfr[ni] = *(const bf16x8*)&Wb[cur][rb][(s ^ (rb & 7)) * 8];
      }
#pragma unroll
      for (int mi = 0; mi < 4; ++mi)
#pragma unroll
        for (int ni = 0; ni < 4; ++ni)
          acc[mi][ni] = __builtin_amdgcn_mfma_f32_16x16x32_bf16(
              af[mi], bfr[ni], acc[mi][ni], 0, 0, 0);
    }
    // boundary: all waves done reading Zs (barrier), then refill for next group
    if ((t == 2) && (c0 + 64 < Cin)) {
      __builtin_amdgcn_s_barrier();
      ZS_GLOAD(c0 + 64);
    }
    // issue W(k+2) AFTER compute (and after Z at boundary, so vmcnt(4) covers Z)
    if (k + 2 < nchunk) WS_ISSUE((k + 2) % 3, ((k + 2) / 3) << 6, (k + 2) % 3);
  }

  // ---- coalesced epilogue: stage tile in LDS (row = strided dim) ----
  __syncthreads();
  const int TP = 136;                 // padded row length (u16)
  u16* tile = smem;                   // 34.8KB <= 65.8KB pool (post-barrier reuse)
  size_t ob = (size_t)b * L * Cout;
  int S, rowbase, colbase;
  if (osc == 1) { S = osl; rowbase = l0; colbase = co0; }
  else          { S = osc; rowbase = co0; colbase = l0; }
#pragma unroll
  for (int ni = 0; ni < 4; ++ni) {
    int c_loc = wc * 64 + ni * 16 + row16;
    float bz = bias[co0 + c_loc];
#pragma unroll
    for (int mi = 0; mi < 4; ++mi) {
#pragma unroll
      for (int r = 0; r < 4; ++r) {
        int l_loc = wr * 64 + mi * 16 + g4 * 4 + r;
        float v = acc[mi][ni][r] + bz;
        if (relu) v = fmaxf(v, 0.f);
        int row = (osc == 1) ? l_loc : c_loc;
        int col = (osc == 1) ? c_loc : l_loc;
        tile[row * TP + col] = f2bf(v);
      }
    }
  }
  __syncthreads();
  for (int e = tid; e < 128 * 16; e += 256) {
    int row = e >> 4, c8 = (e & 15) * 8;
    *(uint4*)(out + ob + (size_t)(rowbase + row) * S + colbase + c8) =
        *(const uint4*)&tile[row * TP + c8];
  }
}

// ---------------- fused cross attention, MFMA (unchanged) ----------------
__global__ __launch_bounds__(256, 4) void attn_mfma_kernel(
    const u16* __restrict__ qh, const u16* __restrict__ kh, const u16* __restrict__ vhT,
    const u16* __restrict__ ql, const u16* __restrict__ kl, const u16* __restrict__ vlT,
    u16* __restrict__ ctx) {
  __shared__ u16 Qs[64][72], Ks[64][72], Vts[64][72];
  __shared__ u16 Ps[64][72];
  __shared__ float rsl[2][2][32];
  int qt = blockIdx.x, h = blockIdx.y, bz = blockIdx.z;
  int b = bz >> 1, br = bz & 1;
  const u16* Q  = br ? ql  : qh;
  const u16* K  = br ? kh  : kl;
  const u16* Vt = br ? vlT : vhT;
  int tid = threadIdx.x;
  int lane = tid & 63, w = tid >> 6, wr = w >> 1, wc = w & 1;
  int row16 = lane & 15, g4 = lane >> 4, k8 = g4 * 8;
  int q0 = qt * 64;
  size_t baseQK = (size_t)b * FEA_ * DM_ + h * 64;
  size_t baseV  = (size_t)b * DM_ * FEA_ + (size_t)(h * 64) * FEA_;
  for (int e = tid; e < 64 * 8; e += 256) {
    int r = e >> 3, c = e & 7;
    *(uint4*)&Qs[r][c * 8] = *(const uint4*)(Q + baseQK + (size_t)(q0 + r) * DM_ + c * 8);
  }
  f32x4 oacc[2][2];
  float rsum[2][4];
#pragma unroll
  for (int i = 0; i < 2; ++i) {
#pragma unroll
    for (int j = 0; j < 2; ++j) oacc[i][j] = (f32x4){0.f, 0.f, 0.f, 0.f};
#pragma unroll
    for (int r = 0; r < 4; ++r) rsum[i][r] = 0.f;
  }
  for (int kt = 0; kt < 8; ++kt) {
    __syncthreads();
    for (int e = tid; e < 64 * 8; e += 256) {
      int r = e >> 3, c = e & 7;
      *(uint4*)&Ks[r][c * 8]  = *(const uint4*)(K + baseQK + (size_t)(kt * 64 + r) * DM_ + c * 8);
      *(uint4*)&Vts[r][c * 8] = *(const uint4*)(Vt + baseV + (size_t)r * FEA_ + kt * 64 + c * 8);
    }
    __syncthreads();
    f32x4 sacc[2][2];
#pragma unroll
    for (int i = 0; i < 2; ++i)
#pragma unroll
      for (int j = 0; j < 2; ++j) sacc[i][j] = (f32x4){0.f, 0.f, 0.f, 0.f};
#pragma unroll
    for (int ks = 0; ks < 2; ++ks) {
      int k0 = ks * 32 + k8;
      bf16x8 a0 = *(const bf16x8*)&Qs[wr * 32 + row16][k0];
      bf16x8 a1 = *(const bf16x8*)&Qs[wr * 32 + 16 + row16][k0];
      bf16x8 b0 = *(const bf16x8*)&Ks[wc * 32 + row16][k0];
      bf16x8 b1 = *(const bf16x8*)&Ks[wc * 32 + 16 + row16][k0];
      sacc[0][0] = __builtin_amdgcn_mfma_f32_16x16x32_bf16(a0, b0, sacc[0][0], 0, 0, 0);
      sacc[0][1] = __builtin_amdgcn_mfma_f32_16x16x32_bf16(a0, b1, sacc[0][1], 0, 0, 0);
      sacc[1][0] = __builtin_amdgcn_mfma_f32_16x16x32_bf16(a1, b0, sacc[1][0], 0, 0, 0);
      sacc[1][1] = __builtin_amdgcn_mfma_f32_16x16x32_bf16(a1, b1, sacc[1][1], 0, 0, 0);
    }
#pragma unroll
    for (int mi = 0; mi < 2; ++mi)
#pragma unroll
      for (int ni = 0; ni < 2; ++ni)
#pragma unroll
        for (int r = 0; r < 4; ++r) {
          float p = __expf(sacc[mi][ni][r] * 0.25f);
          rsum[mi][r] += p;
          Ps[wr * 32 + mi * 16 + g4 * 4 + r][wc * 32 + ni * 16 + row16] = f2bf(p);
        }
    __syncthreads();
#pragma unroll
    for (int ks = 0; ks < 2; ++ks) {
      int k0 = ks * 32 + k8;
      bf16x8 a0 = *(const bf16x8*)&Ps[wr * 32 + row16][k0];
      bf16x8 a1 = *(const bf16x8*)&Ps[wr * 32 + 16 + row16][k0];
      bf16x8 b0 = *(const bf16x8*)&Vts[wc * 32 + row16][k0];
      bf16x8 b1 = *(const bf16x8*)&Vts[wc * 32 + 16 + row16][k0];
      oacc[0][0] = __builtin_amdgcn_mfma_f32_16x16x32_bf16(a0, b0, oacc[0][0], 0, 0, 0);
      oacc[0][1] = __builtin_amdgcn_mfma_f32_16x16x32_bf16(a0, b1, oacc[0][1], 0, 0, 0);
      oacc[1][0] = __builtin_amdgcn_mfma_f32_16x16x32_bf16(a1, b0, oacc[1][0], 0, 0, 0);
      oacc[1][1] = __builtin_amdgcn_mfma_f32_16x16x32_bf16(a1, b1, oacc[1][1], 0, 0, 0);
    }
  }
#pragma unroll
  for (int mi = 0; mi < 2; ++mi)
#pragma unroll
    for (int r = 0; r < 4; ++r) {
#pragma unroll
      for (int m = 1; m < 16; m <<= 1) rsum[mi][r] += __shfl_xor(rsum[mi][r], m);
    }
  if (row16 == 0) {
#pragma unroll
    for (int mi = 0; mi < 2; ++mi)
#pragma unroll
      for (int r = 0; r < 4; ++r) rsl[wr][wc][mi * 16 + g4 * 4 + r] = rsum[mi][r];
  }
  __syncthreads();
#pragma unroll
  for (int mi = 0; mi < 2; ++mi)
#pragma unroll
    for (int ni = 0; ni < 2; ++ni)
#pragma unroll
      for (int r = 0; r < 4; ++r) {
        int qq = mi * 16 + g4 * 4 + r;
        float denom = rsl[wr][0][qq] + rsl[wr][1][qq];
        float o = oacc[mi][ni][r] / denom;
        Ps[wc * 32 + ni * 16 + row16][wr * 32 + qq] = f2bf(o);
      }
  __syncthreads();
  for (int e = tid; e < 64 * 8; e += 256) {
    int r = e >> 3, c = e & 7;
    size_t dst = ((size_t)b * DM_ + h * 64 + r) * (2 * FEA_) + br * 512 + q0 + c * 8;
    *(uint4*)(ctx + dst) = *(const uint4*)&Ps[r][c * 8];
  }
}

// ---------------- LayerNorm over last axis (+optional f32 residual out) ----------------
template <int RESID>
__global__ void ln_kernel(const u16* __restrict__ in, const float* __restrict__ g,
                          const float* __restrict__ beta, const float* __restrict__ resid,
                          void* __restrict__ outp, int C) {
  int row = blockIdx.x;
  int tid = threadIdx.x;
  const u16* p = in + (size_t)row * C;
  float s = 0.f, ss = 0.f;
  for (int c = tid; c < C; c += 256) {
    float v = bf2f(p[c]);
    s += v; ss += v * v;
  }
#pragma unroll
  for (int m = 1; m < 64; m <<= 1) { s += __shfl_xor(s, m); ss += __shfl_xor(ss, m); }
  __shared__ float red[2][4];
  int wid = tid >> 6, lane = tid & 63;
  if (lane == 0) { red[0][wid] = s; red[1][wid] = ss; }
  __syncthreads();
  s  = red[0][0] + red[0][1] + red[0][2] + red[0][3];
  ss = red[1][0] + red[1][1] + red[1][2] + red[1][3];
  float m  = s / C;
  float var = ss / C - m * m;
  float inv = rsqrtf(var + 1e-5f);
  for (int c = tid; c < C; c += 256) {
    float v = (bf2f(p[c]) - m) * inv * g[c] + beta[c];
    if (RESID) ((float*)outp)[(size_t)row * C + c] = v + resid[(size_t)row * C + c];
    else       ((u16*)outp)[(size_t)row * C + c]   = f2bf(v);
  }
}

extern "C" void kernel_launch(void* const* d_in, const int* in_sizes, int n_in,
                              void* d_out, int out_size, void* d_ws, size_t ws_size,
                              hipStream_t stream) {
  (void)in_sizes; (void)n_in; (void)out_size; (void)ws_size;
  const float* x      = (const float*)d_in[0];
  const float* Wq     = (const float*)d_in[1];
  const float* bq     = (const float*)d_in[2];
  const float* Wk     = (const float*)d_in[3];
  const float* bk     = (const float*)d_in[4];
  const float* Wv     = (const float*)d_in[5];
  const float* bv     = (const float*)d_in[6];
  const float* uns_w  = (const float*)d_in[7];
  const float* uns_b  = (const float*)d_in[8];
  const float* cv_w1  = (const float*)d_in[9];
  const float* cv_b1  = (const float*)d_in[10];
  const float* cv_w2  = (const float*)d_in[11];
  const float* cv_b2  = (const float*)d_in[12];
  const float* cv_g   = (const float*)d_in[13];
  const float* cv_beta= (const float*)d_in[14];
  const float* up_w1  = (const float*)d_in[15];
  const float* up_b1  = (const float*)d_in[16];
  const float* up_w2  = (const float*)d_in[17];
  const float* up_b2  = (const float*)d_in[18];
  const float* up_g   = (const float*)d_in[19];
  const float* up_beta= (const float*)d_in[20];

  // ---- workspace plan (peak 112 MiB of d_ws; d_out doubles as scratch) ----
  char* ws = (char*)d_ws;
  const size_t MB = 1ull << 20;
  u16* x1    = (u16*)(ws + 0);
  u16* x2    = (u16*)(ws + 8 * MB);
  u16* qhb   = (u16*)(ws + 16 * MB);
  u16* khb   = (u16*)(ws + 32 * MB);
  u16* vhb   = (u16*)(ws + 48 * MB);   // stored TRANSPOSED: [b][d][fea]
  u16* qlb   = (u16*)(ws + 64 * MB);
  u16* klb   = (u16*)(ws + 80 * MB);
  u16* vlb   = (u16*)(ws + 96 * MB);   // stored TRANSPOSED: [b][d][fea]
  u16* wt_proj = (u16*)d_out;
  u16* ctx   = (u16*)d_out;
  u16* wt_uns = (u16*)(ws + 0);
  u16* ctx2  = (u16*)(ws + 16 * MB);
  u16* wt_cv1 = (u16*)(ws + 32 * MB);
  u16* h1    = (u16*)(ws + 56 * MB);
  u16* wt_cv2 = (u16*)(ws + 32 * MB);
  u16* h2    = (u16*)(ws + 0);
  u16* ctx3  = (u16*)(ws + 8 * MB);
  u16* wt_up1 = (u16*)(ws + 16 * MB);
  u16* h3    = (u16*)(ws + 32 * MB);
  u16* wt_up2 = (u16*)(ws + 64 * MB);
  u16* h4    = (u16*)(ws + 16 * MB);

  dwt_kernel<<<(B_ * FEA_ * HALF_ + 255) / 256, 256, 0, stream>>>(x, x1, x2, B_ * FEA_ * HALF_);

  auto wtr = [&](const float* w, u16* wt, int Cout, int Cin) {
    wtrans_kernel<<<(Cout * Cin * 3 + 255) / 256, 256, 0, stream>>>(w, wt, Cout, Cin);
  };
  auto conv = [&](const u16* Z, const u16* wt, const float* bias, u16* out, int L,
                  int Cin, int Cout, int osl, int osc, int relu) {
    conv_mfma_kernel<<<dim3(L / 128, Cout / 128, B_), 256, 0, stream>>>(
        Z, wt, bias, out, L, Cin, Cout, osl, osc, relu);
  };

  // projections (shared weights across both DWT branches); V written transposed
  wtr(Wq, wt_proj, DM_, HALF_);
  conv(x1, wt_proj, bq, qhb, FEA_, HALF_, DM_, DM_, 1, 0);
  conv(x2, wt_proj, bq, qlb, FEA_, HALF_, DM_, DM_, 1, 0);
  wtr(Wk, wt_proj, DM_, HALF_);
  conv(x1, wt_proj, bk, khb, FEA_, HALF_, DM_, DM_, 1, 0);
  conv(x2, wt_proj, bk, klb, FEA_, HALF_, DM_, DM_, 1, 0);
  wtr(Wv, wt_proj, DM_, HALF_);
  conv(x1, wt_proj, bv, vhb, FEA_, HALF_, DM_, 1, FEA_, 0);
  conv(x2, wt_proj, bv, vlb, FEA_, HALF_, DM_, 1, FEA_, 0);

  attn_mfma_kernel<<<dim3(8, 16, 32), 256, 0, stream>>>(qhb, khb, vhb, qlb, klb, vlb, ctx);

  // unsqueeze conv: conv along d axis, channels 2F->F, transposed write -> ctx2[b][f][d]
  wtr(uns_w, wt_uns, FEA_, 2 * FEA_);
  conv(ctx, wt_uns, uns_b, ctx2, DM_, 2 * FEA_, FEA_, 1, DM_, 0);

  // Convlayer: D_MODEL -> D_FF -> HALF (conv along fea axis), then LN
  wtr(cv_w1, wt_cv1, DFF_, DM_);
  conv(ctx2, wt_cv1, cv_b1, h1, FEA_, DM_, DFF_, DFF_, 1, 1);
  wtr(cv_w2, wt_cv2, HALF_, DFF_);
  conv(h1, wt_cv2, cv_b2, h2, FEA_, DFF_, HALF_, HALF_, 1, 0);
  ln_kernel<0><<<B_ * FEA_, 256, 0, stream>>>(h2, cv_g, cv_beta, nullptr, ctx3, HALF_);

  // upsizeConvlayer: HALF -> D_FF -> D_MODEL, then LN + residual
  wtr(up_w1, wt_up1, DFF_, HALF_);
  conv(ctx3, wt_up1, up_b1, h3, FEA_, HALF_, DFF_, DFF_, 1, 1);
  wtr(up_w2, wt_up2, DM_, DFF_);
  conv(h3, wt_up2, up_b2, h4, FEA_, DFF_, DM_, DM_, 1, 0);
  ln_kernel<1><<<B_ * FEA_, 256, 0, stream>>>(h4, up_g, up_beta, x, d_out, DM_);
}

// Round 13
// 742.857 us; speedup vs baseline: 1.5920x; 1.0077x over previous
//
#include <hip/hip_runtime.h>
#include <hip/hip_bf16.h>

#define B_    16
#define FEA_  512
#define DM_   1024
#define HALF_ 512
#define DFF_  2048

typedef unsigned short u16;
typedef __attribute__((ext_vector_type(8))) short bf16x8;
typedef __attribute__((ext_vector_type(4))) float f32x4;

__device__ __forceinline__ float bf2f(u16 u) {
  union { unsigned int i; float f; } v; v.i = ((unsigned int)u) << 16; return v.f;
}
__device__ __forceinline__ u16 f2bf(float f) {
  union { float f; unsigned int i; } v; v.f = f;
  unsigned int x = v.i;
  return (u16)((x + 0x7fffu + ((x >> 16) & 1u)) >> 16);
}
__device__ __forceinline__ void gload16(const u16* g, u16* l) {
  __builtin_amdgcn_global_load_lds(
      (const __attribute__((address_space(1))) void*)g,
      (__attribute__((address_space(3))) void*)l, 16, 0, 0);
}

// ---------------- DWT (Haar, level 1, last axis) ----------------
__global__ void dwt_kernel(const float* __restrict__ x, u16* __restrict__ x1,
                           u16* __restrict__ x2, int n) {
  int i = blockIdx.x * 256 + threadIdx.x;
  if (i >= n) return;
  float2 v = ((const float2*)x)[i];
  x1[i] = f2bf((v.x + v.y) * 0.70710678118f);
  x2[i] = f2bf((v.x - v.y) * 0.70710678118f);
}

// ---------------- weight transpose (Cout,Cin,3) -> bf16 (3,Cout,Cin) ----------------
__global__ void wtrans_kernel(const float* __restrict__ w, u16* __restrict__ wt,
                              int Cout, int Cin) {
  int e = blockIdx.x * 256 + threadIdx.x;
  if (e >= Cout * Cin * 3) return;
  int co = e / (Cin * 3);
  int r  = e - co * Cin * 3;
  int ci = r / 3;
  int t  = r - ci * 3;
  wt[((size_t)t * Cout + co) * Cin + ci] = f2bf(w[e]);
}

// ---------------- circular conv1d (k=3) as MFMA GEMM ----------------
// Counted-vmcnt pipelined K-loop (r12, verified: 928 TF on cv1-class).
// NEW (r13): XCD-residue grid decode -- 1-D grid, h%8 = XCD residue; all
// co-siblings of one (l_t,b) group share the same residue => same XCD =>
// Z-panel stays L2-resident (was 8.5MB/XCD > 4MB L2 -> thrash; now ~1-2MB).
// NEW (r13): T5 s_setprio around the MFMA cluster (counted-vmcnt rotation
// gives wave role-diversity, the regime where T5 pays per m218b/m224).
#define ZS_GLOAD(c0_)                                                        \
  {                                                                          \
    _Pragma("unroll") for (int i_ = 0; i_ < 5; ++i_) {                       \
      int e_ = tid + i_ * 256;                                               \
      if (e_ < 130 * 8) {                                                    \
        int r_ = e_ >> 3, c_ = e_ & 7;                                       \
        int gl_ = l0 + r_ - 1;                                               \
        if (gl_ < 0) gl_ += L; else if (gl_ >= L) gl_ -= L;                  \
        gload16(Zb + (size_t)gl_ * Cin + (c0_) + ((c_ ^ (r_ & 7)) * 8),      \
                smem + ((size_t)(i_ * 256 + (tid & 192)) * 8));              \
      }                                                                      \
    }                                                                        \
  }
#define WS_ISSUE(t_, c0_, buf_)                                              \
  {                                                                          \
    const u16* Wg_ = Wt + ((size_t)(t_) * Cout + co0) * Cin + (c0_);         \
    int c_ = lane & 7;                                                       \
    _Pragma("unroll") for (int i_ = 0; i_ < 4; ++i_) {                       \
      int rw_ = (i_ * 4 + w) * 8 + (lane >> 3);                              \
      gload16(Wg_ + (size_t)rw_ * Cin + ((c_ ^ (rw_ & 7)) * 8),              \
              &Wb[(buf_)][(i_ * 4 + w) * 8][0]);                             \
    }                                                                        \
  }

__global__ __launch_bounds__(256, 2) void conv_mfma_kernel(
    const u16* __restrict__ Z, const u16* __restrict__ Wt,
    const float* __restrict__ bias, u16* __restrict__ out,
    int L, int Cin, int Cout, int osl, int osc, int relu) {
  __shared__ __align__(16) u16 smem[130 * 64 + 3 * 128 * 64];
  u16 (*Zs)[64] = (u16(*)[64])smem;                        // [130][64]
  u16 (*Wb)[128][64] = (u16(*)[128][64])(smem + 130 * 64); // [3][128][64]
  // ---- XCD-residue decode: groups (l_t,b) with G%8 == h%8 share an XCD ----
  int nl = L >> 7, nco = Cout >> 7;
  int ngroups = nl * B_;          // always divisible by 8 here (nl in {4,8})
  int gper = ngroups >> 3;
  int h = blockIdx.x;
  int r8_ = h & 7, q = h >> 3;
  int g = q % gper, co_t = q / gper;
  int G = r8_ + 8 * g;
  int l_t = G % nl, b = G / nl;
  int l0 = l_t * 128, co0 = co_t * 128;
  int tid = threadIdx.x;
  int lane = tid & 63, w = tid >> 6, wr = w >> 1, wc = w & 1;
  int row16 = lane & 15, g4 = lane >> 4;
  f32x4 acc[4][4];
#pragma unroll
  for (int i = 0; i < 4; ++i)
#pragma unroll
    for (int j = 0; j < 4; ++j) acc[i][j] = (f32x4){0.f, 0.f, 0.f, 0.f};
  const u16* Zb = Z + (size_t)b * L * Cin;

  int nchunk = (Cin >> 6) * 3;
  ZS_GLOAD(0);
  WS_ISSUE(0, 0, 0);
  WS_ISSUE(1, 0, 1);

  for (int k = 0; k < nchunk; ++k) {
    int t = k % 3;
    int c0 = (k / 3) << 6;
    int cur = k % 3;   // buffer index == k%3 (3-buffer rotation)
    if (k + 1 < nchunk) asm volatile("s_waitcnt vmcnt(4)" ::: "memory");
    else                asm volatile("s_waitcnt vmcnt(0)" ::: "memory");
    __builtin_amdgcn_s_barrier();
#pragma unroll
    for (int ks = 0; ks < 2; ++ks) {
      int s = ks * 4 + g4;   // 16B slot index within row
      bf16x8 af[4], bfr[4];
#pragma unroll
      for (int mi = 0; mi < 4; ++mi) {
        int ra = wr * 64 + mi * 16 + row16 + t;
        af[mi] = *(const bf16x8*)&Zs[ra][(s ^ (ra & 7)) * 8];
      }
#pragma unroll
      for (int ni = 0; ni < 4; ++ni) {
        int rb = wc * 64 + ni * 16 + row16;
        bfr[ni] = *(const bf16x8*)&Wb[cur][rb][(s ^ (rb & 7)) * 8];
      }
      __builtin_amdgcn_s_setprio(1);
#pragma unroll
      for (int mi = 0; mi < 4; ++mi)
#pragma unroll
        for (int ni = 0; ni < 4; ++ni)
          acc[mi][ni] = __builtin_amdgcn_mfma_f32_16x16x32_bf16(
              af[mi], bfr[ni], acc[mi][ni], 0, 0, 0);
      __builtin_amdgcn_s_setprio(0);
    }
    if ((t == 2) && (c0 + 64 < Cin)) {
      __builtin_amdgcn_s_barrier();
      ZS_GLOAD(c0 + 64);
    }
    if (k + 2 < nchunk) WS_ISSUE((k + 2) % 3, ((k + 2) / 3) << 6, (k + 2) % 3);
  }

  // ---- coalesced epilogue: stage tile in LDS (row = strided dim) ----
  __syncthreads();
  const int TP = 136;                 // padded row length (u16)
  u16* tile = smem;
  size_t ob = (size_t)b * L * Cout;
  int S, rowbase, colbase;
  if (osc == 1) { S = osl; rowbase = l0; colbase = co0; }
  else          { S = osc; rowbase = co0; colbase = l0; }
#pragma unroll
  for (int ni = 0; ni < 4; ++ni) {
    int c_loc = wc * 64 + ni * 16 + row16;
    float bz = bias[co0 + c_loc];
#pragma unroll
    for (int mi = 0; mi < 4; ++mi) {
#pragma unroll
      for (int r = 0; r < 4; ++r) {
        int l_loc = wr * 64 + mi * 16 + g4 * 4 + r;
        float v = acc[mi][ni][r] + bz;
        if (relu) v = fmaxf(v, 0.f);
        int row = (osc == 1) ? l_loc : c_loc;
        int col = (osc == 1) ? c_loc : l_loc;
        tile[row * TP + col] = f2bf(v);
      }
    }
  }
  __syncthreads();
  for (int e = tid; e < 128 * 16; e += 256) {
    int row = e >> 4, c8 = (e & 15) * 8;
    *(uint4*)(out + ob + (size_t)(rowbase + row) * S + colbase + c8) =
        *(const uint4*)&tile[row * TP + c8];
  }
}

// ---------------- fused cross attention, MFMA (unchanged) ----------------
__global__ __launch_bounds__(256, 4) void attn_mfma_kernel(
    const u16* __restrict__ qh, const u16* __restrict__ kh, const u16* __restrict__ vhT,
    const u16* __restrict__ ql, const u16* __restrict__ kl, const u16* __restrict__ vlT,
    u16* __restrict__ ctx) {
  __shared__ u16 Qs[64][72], Ks[64][72], Vts[64][72];
  __shared__ u16 Ps[64][72];
  __shared__ float rsl[2][2][32];
  int qt = blockIdx.x, h = blockIdx.y, bz = blockIdx.z;
  int b = bz >> 1, br = bz & 1;
  const u16* Q  = br ? ql  : qh;
  const u16* K  = br ? kh  : kl;
  const u16* Vt = br ? vlT : vhT;
  int tid = threadIdx.x;
  int lane = tid & 63, w = tid >> 6, wr = w >> 1, wc = w & 1;
  int row16 = lane & 15, g4 = lane >> 4, k8 = g4 * 8;
  int q0 = qt * 64;
  size_t baseQK = (size_t)b * FEA_ * DM_ + h * 64;
  size_t baseV  = (size_t)b * DM_ * FEA_ + (size_t)(h * 64) * FEA_;
  for (int e = tid; e < 64 * 8; e += 256) {
    int r = e >> 3, c = e & 7;
    *(uint4*)&Qs[r][c * 8] = *(const uint4*)(Q + baseQK + (size_t)(q0 + r) * DM_ + c * 8);
  }
  f32x4 oacc[2][2];
  float rsum[2][4];
#pragma unroll
  for (int i = 0; i < 2; ++i) {
#pragma unroll
    for (int j = 0; j < 2; ++j) oacc[i][j] = (f32x4){0.f, 0.f, 0.f, 0.f};
#pragma unroll
    for (int r = 0; r < 4; ++r) rsum[i][r] = 0.f;
  }
  for (int kt = 0; kt < 8; ++kt) {
    __syncthreads();
    for (int e = tid; e < 64 * 8; e += 256) {
      int r = e >> 3, c = e & 7;
      *(uint4*)&Ks[r][c * 8]  = *(const uint4*)(K + baseQK + (size_t)(kt * 64 + r) * DM_ + c * 8);
      *(uint4*)&Vts[r][c * 8] = *(const uint4*)(Vt + baseV + (size_t)r * FEA_ + kt * 64 + c * 8);
    }
    __syncthreads();
    f32x4 sacc[2][2];
#pragma unroll
    for (int i = 0; i < 2; ++i)
#pragma unroll
      for (int j = 0; j < 2; ++j) sacc[i][j] = (f32x4){0.f, 0.f, 0.f, 0.f};
#pragma unroll
    for (int ks = 0; ks < 2; ++ks) {
      int k0 = ks * 32 + k8;
      bf16x8 a0 = *(const bf16x8*)&Qs[wr * 32 + row16][k0];
      bf16x8 a1 = *(const bf16x8*)&Qs[wr * 32 + 16 + row16][k0];
      bf16x8 b0 = *(const bf16x8*)&Ks[wc * 32 + row16][k0];
      bf16x8 b1 = *(const bf16x8*)&Ks[wc * 32 + 16 + row16][k0];
      sacc[0][0] = __builtin_amdgcn_mfma_f32_16x16x32_bf16(a0, b0, sacc[0][0], 0, 0, 0);
      sacc[0][1] = __builtin_amdgcn_mfma_f32_16x16x32_bf16(a0, b1, sacc[0][1], 0, 0, 0);
      sacc[1][0] = __builtin_amdgcn_mfma_f32_16x16x32_bf16(a1, b0, sacc[1][0], 0, 0, 0);
      sacc[1][1] = __builtin_amdgcn_mfma_f32_16x16x32_bf16(a1, b1, sacc[1][1], 0, 0, 0);
    }
#pragma unroll
    for (int mi = 0; mi < 2; ++mi)
#pragma unroll
      for (int ni = 0; ni < 2; ++ni)
#pragma unroll
        for (int r = 0; r < 4; ++r) {
          float p = __expf(sacc[mi][ni][r] * 0.25f);
          rsum[mi][r] += p;
          Ps[wr * 32 + mi * 16 + g4 * 4 + r][wc * 32 + ni * 16 + row16] = f2bf(p);
        }
    __syncthreads();
#pragma unroll
    for (int ks = 0; ks < 2; ++ks) {
      int k0 = ks * 32 + k8;
      bf16x8 a0 = *(const bf16x8*)&Ps[wr * 32 + row16][k0];
      bf16x8 a1 = *(const bf16x8*)&Ps[wr * 32 + 16 + row16][k0];
      bf16x8 b0 = *(const bf16x8*)&Vts[wc * 32 + row16][k0];
      bf16x8 b1 = *(const bf16x8*)&Vts[wc * 32 + 16 + row16][k0];
      oacc[0][0] = __builtin_amdgcn_mfma_f32_16x16x32_bf16(a0, b0, oacc[0][0], 0, 0, 0);
      oacc[0][1] = __builtin_amdgcn_mfma_f32_16x16x32_bf16(a0, b1, oacc[0][1], 0, 0, 0);
      oacc[1][0] = __builtin_amdgcn_mfma_f32_16x16x32_bf16(a1, b0, oacc[1][0], 0, 0, 0);
      oacc[1][1] = __builtin_amdgcn_mfma_f32_16x16x32_bf16(a1, b1, oacc[1][1], 0, 0, 0);
    }
  }
#pragma unroll
  for (int mi = 0; mi < 2; ++mi)
#pragma unroll
    for (int r = 0; r < 4; ++r) {
#pragma unroll
      for (int m = 1; m < 16; m <<= 1) rsum[mi][r] += __shfl_xor(rsum[mi][r], m);
    }
  if (row16 == 0) {
#pragma unroll
    for (int mi = 0; mi < 2; ++mi)
#pragma unroll
      for (int r = 0; r < 4; ++r) rsl[wr][wc][mi * 16 + g4 * 4 + r] = rsum[mi][r];
  }
  __syncthreads();
#pragma unroll
  for (int mi = 0; mi < 2; ++mi)
#pragma unroll
    for (int ni = 0; ni < 2; ++ni)
#pragma unroll
      for (int r = 0; r < 4; ++r) {
        int qq = mi * 16 + g4 * 4 + r;
        float denom = rsl[wr][0][qq] + rsl[wr][1][qq];
        float o = oacc[mi][ni][r] / denom;
        Ps[wc * 32 + ni * 16 + row16][wr * 32 + qq] = f2bf(o);
      }
  __syncthreads();
  for (int e = tid; e < 64 * 8; e += 256) {
    int r = e >> 3, c = e & 7;
    size_t dst = ((size_t)b * DM_ + h * 64 + r) * (2 * FEA_) + br * 512 + q0 + c * 8;
    *(uint4*)(ctx + dst) = *(const uint4*)&Ps[r][c * 8];
  }
}

// ---------------- LayerNorm over last axis (+optional f32 residual out) ----------------
template <int RESID>
__global__ void ln_kernel(const u16* __restrict__ in, const float* __restrict__ g,
                          const float* __restrict__ beta, const float* __restrict__ resid,
                          void* __restrict__ outp, int C) {
  int row = blockIdx.x;
  int tid = threadIdx.x;
  const u16* p = in + (size_t)row * C;
  float s = 0.f, ss = 0.f;
  for (int c = tid; c < C; c += 256) {
    float v = bf2f(p[c]);
    s += v; ss += v * v;
  }
#pragma unroll
  for (int m = 1; m < 64; m <<= 1) { s += __shfl_xor(s, m); ss += __shfl_xor(ss, m); }
  __shared__ float red[2][4];
  int wid = tid >> 6, lane = tid & 63;
  if (lane == 0) { red[0][wid] = s; red[1][wid] = ss; }
  __syncthreads();
  s  = red[0][0] + red[0][1] + red[0][2] + red[0][3];
  ss = red[1][0] + red[1][1] + red[1][2] + red[1][3];
  float m  = s / C;
  float var = ss / C - m * m;
  float inv = rsqrtf(var + 1e-5f);
  for (int c = tid; c < C; c += 256) {
    float v = (bf2f(p[c]) - m) * inv * g[c] + beta[c];
    if (RESID) ((float*)outp)[(size_t)row * C + c] = v + resid[(size_t)row * C + c];
    else       ((u16*)outp)[(size_t)row * C + c]   = f2bf(v);
  }
}

extern "C" void kernel_launch(void* const* d_in, const int* in_sizes, int n_in,
                              void* d_out, int out_size, void* d_ws, size_t ws_size,
                              hipStream_t stream) {
  (void)in_sizes; (void)n_in; (void)out_size; (void)ws_size;
  const float* x      = (const float*)d_in[0];
  const float* Wq     = (const float*)d_in[1];
  const float* bq     = (const float*)d_in[2];
  const float* Wk     = (const float*)d_in[3];
  const float* bk     = (const float*)d_in[4];
  const float* Wv     = (const float*)d_in[5];
  const float* bv     = (const float*)d_in[6];
  const float* uns_w  = (const float*)d_in[7];
  const float* uns_b  = (const float*)d_in[8];
  const float* cv_w1  = (const float*)d_in[9];
  const float* cv_b1  = (const float*)d_in[10];
  const float* cv_w2  = (const float*)d_in[11];
  const float* cv_b2  = (const float*)d_in[12];
  const float* cv_g   = (const float*)d_in[13];
  const float* cv_beta= (const float*)d_in[14];
  const float* up_w1  = (const float*)d_in[15];
  const float* up_b1  = (const float*)d_in[16];
  const float* up_w2  = (const float*)d_in[17];
  const float* up_b2  = (const float*)d_in[18];
  const float* up_g   = (const float*)d_in[19];
  const float* up_beta= (const float*)d_in[20];

  // ---- workspace plan (peak 112 MiB of d_ws; d_out doubles as scratch) ----
  char* ws = (char*)d_ws;
  const size_t MB = 1ull << 20;
  u16* x1    = (u16*)(ws + 0);
  u16* x2    = (u16*)(ws + 8 * MB);
  u16* qhb   = (u16*)(ws + 16 * MB);
  u16* khb   = (u16*)(ws + 32 * MB);
  u16* vhb   = (u16*)(ws + 48 * MB);   // stored TRANSPOSED: [b][d][fea]
  u16* qlb   = (u16*)(ws + 64 * MB);
  u16* klb   = (u16*)(ws + 80 * MB);
  u16* vlb   = (u16*)(ws + 96 * MB);   // stored TRANSPOSED: [b][d][fea]
  u16* wt_proj = (u16*)d_out;
  u16* ctx   = (u16*)d_out;
  u16* wt_uns = (u16*)(ws + 0);
  u16* ctx2  = (u16*)(ws + 16 * MB);
  u16* wt_cv1 = (u16*)(ws + 32 * MB);
  u16* h1    = (u16*)(ws + 56 * MB);
  u16* wt_cv2 = (u16*)(ws + 32 * MB);
  u16* h2    = (u16*)(ws + 0);
  u16* ctx3  = (u16*)(ws + 8 * MB);
  u16* wt_up1 = (u16*)(ws + 16 * MB);
  u16* h3    = (u16*)(ws + 32 * MB);
  u16* wt_up2 = (u16*)(ws + 64 * MB);
  u16* h4    = (u16*)(ws + 16 * MB);

  dwt_kernel<<<(B_ * FEA_ * HALF_ + 255) / 256, 256, 0, stream>>>(x, x1, x2, B_ * FEA_ * HALF_);

  auto wtr = [&](const float* w, u16* wt, int Cout, int Cin) {
    wtrans_kernel<<<(Cout * Cin * 3 + 255) / 256, 256, 0, stream>>>(w, wt, Cout, Cin);
  };
  auto conv = [&](const u16* Z, const u16* wt, const float* bias, u16* out, int L,
                  int Cin, int Cout, int osl, int osc, int relu) {
    int nblk = (L >> 7) * (Cout >> 7) * B_;
    conv_mfma_kernel<<<nblk, 256, 0, stream>>>(Z, wt, bias, out, L, Cin, Cout, osl, osc, relu);
  };

  // projections (shared weights across both DWT branches); V written transposed
  wtr(Wq, wt_proj, DM_, HALF_);
  conv(x1, wt_proj, bq, qhb, FEA_, HALF_, DM_, DM_, 1, 0);
  conv(x2, wt_proj, bq, qlb, FEA_, HALF_, DM_, DM_, 1, 0);
  wtr(Wk, wt_proj, DM_, HALF_);
  conv(x1, wt_proj, bk, khb, FEA_, HALF_, DM_, DM_, 1, 0);
  conv(x2, wt_proj, bk, klb, FEA_, HALF_, DM_, DM_, 1, 0);
  wtr(Wv, wt_proj, DM_, HALF_);
  conv(x1, wt_proj, bv, vhb, FEA_, HALF_, DM_, 1, FEA_, 0);
  conv(x2, wt_proj, bv, vlb, FEA_, HALF_, DM_, 1, FEA_, 0);

  attn_mfma_kernel<<<dim3(8, 16, 32), 256, 0, stream>>>(qhb, khb, vhb, qlb, klb, vlb, ctx);

  // unsqueeze conv: conv along d axis, channels 2F->F, transposed write -> ctx2[b][f][d]
  wtr(uns_w, wt_uns, FEA_, 2 * FEA_);
  conv(ctx, wt_uns, uns_b, ctx2, DM_, 2 * FEA_, FEA_, 1, DM_, 0);

  // Convlayer: D_MODEL -> D_FF -> HALF (conv along fea axis), then LN
  wtr(cv_w1, wt_cv1, DFF_, DM_);
  conv(ctx2, wt_cv1, cv_b1, h1, FEA_, DM_, DFF_, DFF_, 1, 1);
  wtr(cv_w2, wt_cv2, HALF_, DFF_);
  conv(h1, wt_cv2, cv_b2, h2, FEA_, DFF_, HALF_, HALF_, 1, 0);
  ln_kernel<0><<<B_ * FEA_, 256, 0, stream>>>(h2, cv_g, cv_beta, nullptr, ctx3, HALF_);

  // upsizeConvlayer: HALF -> D_FF -> D_MODEL, then LN + residual
  wtr(up_w1, wt_up1, DFF_, HALF_);
  conv(ctx3, wt_up1, up_b1, h3, FEA_, HALF_, DFF_, DFF_, 1, 1);
  wtr(up_w2, wt_up2, DM_, DFF_);
  conv(h3, wt_up2, up_b2, h4, FEA_, DFF_, DM_, DM_, 1, 0);
  ln_kernel<1><<<B_ * FEA_, 256, 0, stream>>>(h4, up_g, up_beta, x, d_out, DM_);
}

// Round 14
// 713.039 us; speedup vs baseline: 1.6586x; 1.0418x over previous
//
#include <hip/hip_runtime.h>
#include <hip/hip_bf16.h>

#define B_    16
#define FEA_  512
#define DM_   1024
#define HALF_ 512
#define DFF_  2048

typedef unsigned short u16;
typedef __attribute__((ext_vector_type(8))) short bf16x8;
typedef __attribute__((ext_vector_type(4))) float f32x4;

__device__ __forceinline__ float bf2f(u16 u) {
  union { unsigned int i; float f; } v; v.i = ((unsigned int)u) << 16; return v.f;
}
__device__ __forceinline__ u16 f2bf(float f) {
  union { float f; unsigned int i; } v; v.f = f;
  unsigned int x = v.i;
  return (u16)((x + 0x7fffu + ((x >> 16) & 1u)) >> 16);
}
__device__ __forceinline__ void gload16(const u16* g, u16* l) {
  __builtin_amdgcn_global_load_lds(
      (const __attribute__((address_space(1))) void*)g,
      (__attribute__((address_space(3))) void*)l, 16, 0, 0);
}

// ---------------- DWT (Haar, level 1, last axis) ----------------
__global__ void dwt_kernel(const float* __restrict__ x, u16* __restrict__ x1,
                           u16* __restrict__ x2, int n) {
  int i = blockIdx.x * 256 + threadIdx.x;
  if (i >= n) return;
  float2 v = ((const float2*)x)[i];
  x1[i] = f2bf((v.x + v.y) * 0.70710678118f);
  x2[i] = f2bf((v.x - v.y) * 0.70710678118f);
}

// ---------------- weight transpose, fused variants ----------------
// (Cout,Cin,3) f32 -> (3,Cout,Cin) bf16
__global__ void wtrans3_kernel(const float* __restrict__ w0, const float* __restrict__ w1,
                               const float* __restrict__ w2, u16* __restrict__ wt,
                               int Cout, int Cin) {
  int n = Cout * Cin * 3;
  int e = blockIdx.x * 256 + threadIdx.x;
  if (e >= 3 * n) return;
  int i = e / n, le = e - i * n;
  const float* w = (i == 0) ? w0 : ((i == 1) ? w1 : w2);
  int co = le / (Cin * 3);
  int r  = le - co * Cin * 3;
  int ci = r / 3;
  int t  = r - ci * 3;
  wt[(size_t)i * n + ((size_t)t * Cout + co) * Cin + ci] = f2bf(w[le]);
}

struct WTSeg { const float* src; u16* dst; int cout, cin, base; };
struct WT5 { WTSeg s[5]; int total; };
__global__ void wtrans5_kernel(WT5 p) {
  int e = blockIdx.x * 256 + threadIdx.x;
  if (e >= p.total) return;
#pragma unroll
  for (int i = 0; i < 5; ++i) {
    int Cin = p.s[i].cin, Cout = p.s[i].cout;
    int n = Cout * Cin * 3;
    int le = e - p.s[i].base;
    if (le >= 0 && le < n) {
      int co = le / (Cin * 3);
      int r  = le - co * Cin * 3;
      int ci = r / 3;
      int t  = r - ci * 3;
      p.s[i].dst[((size_t)t * Cout + co) * Cin + ci] = f2bf(p.s[i].src[le]);
    }
  }
}

// ---------------- circular conv1d (k=3) as MFMA GEMM ----------------
// Counted-vmcnt pipelined K-loop (r12-verified): chunk k reads Wb[k%3];
// W(k+2) issued at END of chunk k (3 buffers, 2-deep). Per-chunk wait =
// s_waitcnt vmcnt(4) + raw s_barrier. Z staged via global_load_lds
// (source-swizzled, dest lane-linear) at ci-group boundaries.
#define ZS_GLOAD(c0_)                                                        \
  {                                                                          \
    _Pragma("unroll") for (int i_ = 0; i_ < 5; ++i_) {                       \
      int e_ = tid + i_ * 256;                                               \
      if (e_ < 130 * 8) {                                                    \
        int r_ = e_ >> 3, c_ = e_ & 7;                                       \
        int gl_ = l0 + r_ - 1;                                               \
        if (gl_ < 0) gl_ += L; else if (gl_ >= L) gl_ -= L;                  \
        gload16(Zb + (size_t)gl_ * Cin + (c0_) + ((c_ ^ (r_ & 7)) * 8),      \
                smem + ((size_t)(i_ * 256 + (tid & 192)) * 8));              \
      }                                                                      \
    }                                                                        \
  }
#define WS_ISSUE(t_, c0_, buf_)                                              \
  {                                                                          \
    const u16* Wg_ = Wt + ((size_t)(t_) * Cout + co0) * Cin + (c0_);         \
    int c_ = lane & 7;                                                       \
    _Pragma("unroll") for (int i_ = 0; i_ < 4; ++i_) {                       \
      int rw_ = (i_ * 4 + w) * 8 + (lane >> 3);                              \
      gload16(Wg_ + (size_t)rw_ * Cin + ((c_ ^ (rw_ & 7)) * 8),              \
              &Wb[(buf_)][(i_ * 4 + w) * 8][0]);                             \
    }                                                                        \
  }

__global__ __launch_bounds__(256, 2) void conv_mfma_kernel(
    const u16* __restrict__ Z, const u16* __restrict__ Wt,
    const float* __restrict__ bias, u16* __restrict__ out,
    int L, int Cin, int Cout, int osl, int osc, int relu) {
  __shared__ __align__(16) u16 smem[130 * 64 + 3 * 128 * 64];
  u16 (*Zs)[64] = (u16(*)[64])smem;                        // [130][64]
  u16 (*Wb)[128][64] = (u16(*)[128][64])(smem + 130 * 64); // [3][128][64]
  int l0 = blockIdx.x * 128, co0 = blockIdx.y * 128, b = blockIdx.z;
  int tid = threadIdx.x;
  int lane = tid & 63, w = tid >> 6, wr = w >> 1, wc = w & 1;
  int row16 = lane & 15, g4 = lane >> 4;
  f32x4 acc[4][4];
#pragma unroll
  for (int i = 0; i < 4; ++i)
#pragma unroll
    for (int j = 0; j < 4; ++j) acc[i][j] = (f32x4){0.f, 0.f, 0.f, 0.f};
  const u16* Zb = Z + (size_t)b * L * Cin;

  int nchunk = (Cin >> 6) * 3;
  ZS_GLOAD(0);
  WS_ISSUE(0, 0, 0);
  WS_ISSUE(1, 0, 1);

  for (int k = 0; k < nchunk; ++k) {
    int t = k % 3;
    int c0 = (k / 3) << 6;
    int cur = k % 3;
    if (k + 1 < nchunk) asm volatile("s_waitcnt vmcnt(4)" ::: "memory");
    else                asm volatile("s_waitcnt vmcnt(0)" ::: "memory");
    __builtin_amdgcn_s_barrier();
#pragma unroll
    for (int ks = 0; ks < 2; ++ks) {
      int s = ks * 4 + g4;
      bf16x8 af[4], bfr[4];
#pragma unroll
      for (int mi = 0; mi < 4; ++mi) {
        int ra = wr * 64 + mi * 16 + row16 + t;
        af[mi] = *(const bf16x8*)&Zs[ra][(s ^ (ra & 7)) * 8];
      }
#pragma unroll
      for (int ni = 0; ni < 4; ++ni) {
        int rb = wc * 64 + ni * 16 + row16;
        bfr[ni] = *(const bf16x8*)&Wb[cur][rb][(s ^ (rb & 7)) * 8];
      }
      __builtin_amdgcn_s_setprio(1);
#pragma unroll
      for (int mi = 0; mi < 4; ++mi)
#pragma unroll
        for (int ni = 0; ni < 4; ++ni)
          acc[mi][ni] = __builtin_amdgcn_mfma_f32_16x16x32_bf16(
              af[mi], bfr[ni], acc[mi][ni], 0, 0, 0);
      __builtin_amdgcn_s_setprio(0);
    }
    if ((t == 2) && (c0 + 64 < Cin)) {
      __builtin_amdgcn_s_barrier();
      ZS_GLOAD(c0 + 64);
    }
    if (k + 2 < nchunk) WS_ISSUE((k + 2) % 3, ((k + 2) / 3) << 6, (k + 2) % 3);
  }

  // ---- coalesced epilogue: stage tile in LDS (row = strided dim) ----
  __syncthreads();
  const int TP = 136;
  u16* tile = smem;
  size_t ob = (size_t)b * L * Cout;
  int S, rowbase, colbase;
  if (osc == 1) { S = osl; rowbase = l0; colbase = co0; }
  else          { S = osc; rowbase = co0; colbase = l0; }
#pragma unroll
  for (int ni = 0; ni < 4; ++ni) {
    int c_loc = wc * 64 + ni * 16 + row16;
    float bz = bias[co0 + c_loc];
#pragma unroll
    for (int mi = 0; mi < 4; ++mi) {
#pragma unroll
      for (int r = 0; r < 4; ++r) {
        int l_loc = wr * 64 + mi * 16 + g4 * 4 + r;
        float v = acc[mi][ni][r] + bz;
        if (relu) v = fmaxf(v, 0.f);
        int row = (osc == 1) ? l_loc : c_loc;
        int col = (osc == 1) ? c_loc : l_loc;
        tile[row * TP + col] = f2bf(v);
      }
    }
  }
  __syncthreads();
  for (int e = tid; e < 128 * 16; e += 256) {
    int row = e >> 4, c8 = (e & 15) * 8;
    *(uint4*)(out + ob + (size_t)(rowbase + row) * S + colbase + c8) =
        *(const uint4*)&tile[row * TP + c8];
  }
}

// ---------------- fused cross attention, MFMA (unchanged) ----------------
__global__ __launch_bounds__(256, 4) void attn_mfma_kernel(
    const u16* __restrict__ qh, const u16* __restrict__ kh, const u16* __restrict__ vhT,
    const u16* __restrict__ ql, const u16* __restrict__ kl, const u16* __restrict__ vlT,
    u16* __restrict__ ctx) {
  __shared__ u16 Qs[64][72], Ks[64][72], Vts[64][72];
  __shared__ u16 Ps[64][72];
  __shared__ float rsl[2][2][32];
  int qt = blockIdx.x, h = blockIdx.y, bz = blockIdx.z;
  int b = bz >> 1, br = bz & 1;
  const u16* Q  = br ? ql  : qh;
  const u16* K  = br ? kh  : kl;
  const u16* Vt = br ? vlT : vhT;
  int tid = threadIdx.x;
  int lane = tid & 63, w = tid >> 6, wr = w >> 1, wc = w & 1;
  int row16 = lane & 15, g4 = lane >> 4, k8 = g4 * 8;
  int q0 = qt * 64;
  size_t baseQK = (size_t)b * FEA_ * DM_ + h * 64;
  size_t baseV  = (size_t)b * DM_ * FEA_ + (size_t)(h * 64) * FEA_;
  for (int e = tid; e < 64 * 8; e += 256) {
    int r = e >> 3, c = e & 7;
    *(uint4*)&Qs[r][c * 8] = *(const uint4*)(Q + baseQK + (size_t)(q0 + r) * DM_ + c * 8);
  }
  f32x4 oacc[2][2];
  float rsum[2][4];
#pragma unroll
  for (int i = 0; i < 2; ++i) {
#pragma unroll
    for (int j = 0; j < 2; ++j) oacc[i][j] = (f32x4){0.f, 0.f, 0.f, 0.f};
#pragma unroll
    for (int r = 0; r < 4; ++r) rsum[i][r] = 0.f;
  }
  for (int kt = 0; kt < 8; ++kt) {
    __syncthreads();
    for (int e = tid; e < 64 * 8; e += 256) {
      int r = e >> 3, c = e & 7;
      *(uint4*)&Ks[r][c * 8]  = *(const uint4*)(K + baseQK + (size_t)(kt * 64 + r) * DM_ + c * 8);
      *(uint4*)&Vts[r][c * 8] = *(const uint4*)(Vt + baseV + (size_t)r * FEA_ + kt * 64 + c * 8);
    }
    __syncthreads();
    f32x4 sacc[2][2];
#pragma unroll
    for (int i = 0; i < 2; ++i)
#pragma unroll
      for (int j = 0; j < 2; ++j) sacc[i][j] = (f32x4){0.f, 0.f, 0.f, 0.f};
#pragma unroll
    for (int ks = 0; ks < 2; ++ks) {
      int k0 = ks * 32 + k8;
      bf16x8 a0 = *(const bf16x8*)&Qs[wr * 32 + row16][k0];
      bf16x8 a1 = *(const bf16x8*)&Qs[wr * 32 + 16 + row16][k0];
      bf16x8 b0 = *(const bf16x8*)&Ks[wc * 32 + row16][k0];
      bf16x8 b1 = *(const bf16x8*)&Ks[wc * 32 + 16 + row16][k0];
      sacc[0][0] = __builtin_amdgcn_mfma_f32_16x16x32_bf16(a0, b0, sacc[0][0], 0, 0, 0);
      sacc[0][1] = __builtin_amdgcn_mfma_f32_16x16x32_bf16(a0, b1, sacc[0][1], 0, 0, 0);
      sacc[1][0] = __builtin_amdgcn_mfma_f32_16x16x32_bf16(a1, b0, sacc[1][0], 0, 0, 0);
      sacc[1][1] = __builtin_amdgcn_mfma_f32_16x16x32_bf16(a1, b1, sacc[1][1], 0, 0, 0);
    }
#pragma unroll
    for (int mi = 0; mi < 2; ++mi)
#pragma unroll
      for (int ni = 0; ni < 2; ++ni)
#pragma unroll
        for (int r = 0; r < 4; ++r) {
          float p = __expf(sacc[mi][ni][r] * 0.25f);
          rsum[mi][r] += p;
          Ps[wr * 32 + mi * 16 + g4 * 4 + r][wc * 32 + ni * 16 + row16] = f2bf(p);
        }
    __syncthreads();
#pragma unroll
    for (int ks = 0; ks < 2; ++ks) {
      int k0 = ks * 32 + k8;
      bf16x8 a0 = *(const bf16x8*)&Ps[wr * 32 + row16][k0];
      bf16x8 a1 = *(const bf16x8*)&Ps[wr * 32 + 16 + row16][k0];
      bf16x8 b0 = *(const bf16x8*)&Vts[wc * 32 + row16][k0];
      bf16x8 b1 = *(const bf16x8*)&Vts[wc * 32 + 16 + row16][k0];
      oacc[0][0] = __builtin_amdgcn_mfma_f32_16x16x32_bf16(a0, b0, oacc[0][0], 0, 0, 0);
      oacc[0][1] = __builtin_amdgcn_mfma_f32_16x16x32_bf16(a0, b1, oacc[0][1], 0, 0, 0);
      oacc[1][0] = __builtin_amdgcn_mfma_f32_16x16x32_bf16(a1, b0, oacc[1][0], 0, 0, 0);
      oacc[1][1] = __builtin_amdgcn_mfma_f32_16x16x32_bf16(a1, b1, oacc[1][1], 0, 0, 0);
    }
  }
#pragma unroll
  for (int mi = 0; mi < 2; ++mi)
#pragma unroll
    for (int r = 0; r < 4; ++r) {
#pragma unroll
      for (int m = 1; m < 16; m <<= 1) rsum[mi][r] += __shfl_xor(rsum[mi][r], m);
    }
  if (row16 == 0) {
#pragma unroll
    for (int mi = 0; mi < 2; ++mi)
#pragma unroll
      for (int r = 0; r < 4; ++r) rsl[wr][wc][mi * 16 + g4 * 4 + r] = rsum[mi][r];
  }
  __syncthreads();
#pragma unroll
  for (int mi = 0; mi < 2; ++mi)
#pragma unroll
    for (int ni = 0; ni < 2; ++ni)
#pragma unroll
      for (int r = 0; r < 4; ++r) {
        int qq = mi * 16 + g4 * 4 + r;
        float denom = rsl[wr][0][qq] + rsl[wr][1][qq];
        float o = oacc[mi][ni][r] / denom;
        Ps[wc * 32 + ni * 16 + row16][wr * 32 + qq] = f2bf(o);
      }
  __syncthreads();
  for (int e = tid; e < 64 * 8; e += 256) {
    int r = e >> 3, c = e & 7;
    size_t dst = ((size_t)b * DM_ + h * 64 + r) * (2 * FEA_) + br * 512 + q0 + c * 8;
    *(uint4*)(ctx + dst) = *(const uint4*)&Ps[r][c * 8];
  }
}

// ---------------- LayerNorm over last axis (+optional f32 residual out) ----------------
template <int RESID>
__global__ void ln_kernel(const u16* __restrict__ in, const float* __restrict__ g,
                          const float* __restrict__ beta, const float* __restrict__ resid,
                          void* __restrict__ outp, int C) {
  int row = blockIdx.x;
  int tid = threadIdx.x;
  const u16* p = in + (size_t)row * C;
  float s = 0.f, ss = 0.f;
  for (int c = tid; c < C; c += 256) {
    float v = bf2f(p[c]);
    s += v; ss += v * v;
  }
#pragma unroll
  for (int m = 1; m < 64; m <<= 1) { s += __shfl_xor(s, m); ss += __shfl_xor(ss, m); }
  __shared__ float red[2][4];
  int wid = tid >> 6, lane = tid & 63;
  if (lane == 0) { red[0][wid] = s; red[1][wid] = ss; }
  __syncthreads();
  s  = red[0][0] + red[0][1] + red[0][2] + red[0][3];
  ss = red[1][0] + red[1][1] + red[1][2] + red[1][3];
  float m  = s / C;
  float var = ss / C - m * m;
  float inv = rsqrtf(var + 1e-5f);
  for (int c = tid; c < C; c += 256) {
    float v = (bf2f(p[c]) - m) * inv * g[c] + beta[c];
    if (RESID) ((float*)outp)[(size_t)row * C + c] = v + resid[(size_t)row * C + c];
    else       ((u16*)outp)[(size_t)row * C + c]   = f2bf(v);
  }
}

extern "C" void kernel_launch(void* const* d_in, const int* in_sizes, int n_in,
                              void* d_out, int out_size, void* d_ws, size_t ws_size,
                              hipStream_t stream) {
  (void)in_sizes; (void)n_in; (void)out_size; (void)ws_size;
  const float* x      = (const float*)d_in[0];
  const float* Wq     = (const float*)d_in[1];
  const float* bq     = (const float*)d_in[2];
  const float* Wk     = (const float*)d_in[3];
  const float* bk     = (const float*)d_in[4];
  const float* Wv     = (const float*)d_in[5];
  const float* bv     = (const float*)d_in[6];
  const float* uns_w  = (const float*)d_in[7];
  const float* uns_b  = (const float*)d_in[8];
  const float* cv_w1  = (const float*)d_in[9];
  const float* cv_b1  = (const float*)d_in[10];
  const float* cv_w2  = (const float*)d_in[11];
  const float* cv_b2  = (const float*)d_in[12];
  const float* cv_g   = (const float*)d_in[13];
  const float* cv_beta= (const float*)d_in[14];
  const float* up_w1  = (const float*)d_in[15];
  const float* up_b1  = (const float*)d_in[16];
  const float* up_w2  = (const float*)d_in[17];
  const float* up_b2  = (const float*)d_in[18];
  const float* up_g   = (const float*)d_in[19];
  const float* up_beta= (const float*)d_in[20];

  // ---- workspace plan (peak 112 MiB; d_out doubles as scratch) ----
  // phase A (dwt+proj):   x1[0,8) x2[8,16)  qhb[16,32) qlb[32,48) khb[48,64)
  //                       klb[64,80) vhb[80,96) vlb[96,112)  wt_proj = d_out
  //                       (x1,x2 contiguous => proj convs batched as B=32;
  //                        q/k/v outputs contiguous across both branches)
  // phase B (attn):       reads qkv, writes ctx = d_out
  // phase C (wtrans5):    wt_uns[0,4) wt_cv1[4,17) wt_cv2[17,24) wt_up1[24,31)
  //                       wt_up2[31,44)   (qkv regions dead)
  // phase D (ffn):        ctx2[48,64) h1[64,96) h2[96,104) ctx3[104,112)
  //                       h3[64,96) (h1 dead)  h4[48,64) (ctx2 dead)
  char* ws = (char*)d_ws;
  const size_t MB = 1ull << 20;
  u16* x1    = (u16*)(ws + 0);
  u16* x1x2  = x1;                      // 32 virtual batches
  u16* qhb   = (u16*)(ws + 16 * MB);    // [qhb|qlb] contiguous
  u16* khb   = (u16*)(ws + 48 * MB);    // [khb|klb] contiguous
  u16* vhb   = (u16*)(ws + 80 * MB);    // [vhbT|vlbT] contiguous
  u16* qlb   = (u16*)(ws + 32 * MB);
  u16* klb   = (u16*)(ws + 64 * MB);
  u16* vlb   = (u16*)(ws + 96 * MB);
  u16* wt_proj = (u16*)d_out;           // 3 x 3.1 MiB, dead before attn
  u16* ctx   = (u16*)d_out;
  u16* wt_uns  = (u16*)(ws + 0);
  u16* wt_cv1  = (u16*)(ws + 4 * MB);
  u16* wt_cv2  = (u16*)(ws + 17 * MB);
  u16* wt_up1  = (u16*)(ws + 24 * MB);
  u16* wt_up2  = (u16*)(ws + 31 * MB);
  u16* ctx2  = (u16*)(ws + 48 * MB);
  u16* h1    = (u16*)(ws + 64 * MB);
  u16* h2    = (u16*)(ws + 96 * MB);
  u16* ctx3  = (u16*)(ws + 104 * MB);
  u16* h3    = (u16*)(ws + 64 * MB);
  u16* h4    = (u16*)(ws + 48 * MB);

  dwt_kernel<<<(B_ * FEA_ * HALF_ + 255) / 256, 256, 0, stream>>>(x, x1, (u16*)(ws + 8 * MB),
                                                                  B_ * FEA_ * HALF_);

  // fused Q/K/V weight transpose -> wt_proj (3 segments of DM_*HALF_*3)
  const int NPROJ = DM_ * HALF_ * 3;
  wtrans3_kernel<<<(3 * NPROJ + 255) / 256, 256, 0, stream>>>(Wq, Wk, Wv, wt_proj, DM_, HALF_);

  auto conv = [&](const u16* Z, const u16* wt, const float* bias, u16* out, int L,
                  int Cin, int Cout, int osl, int osc, int relu, int nb) {
    conv_mfma_kernel<<<dim3(L / 128, Cout / 128, nb), 256, 0, stream>>>(
        Z, wt, bias, out, L, Cin, Cout, osl, osc, relu);
  };

  // projections, both DWT branches batched (B=32); V written transposed
  conv(x1x2, wt_proj,              bq, qhb, FEA_, HALF_, DM_, DM_, 1, 0, 32);
  conv(x1x2, wt_proj + NPROJ,      bk, khb, FEA_, HALF_, DM_, DM_, 1, 0, 32);
  conv(x1x2, wt_proj + 2 * NPROJ,  bv, vhb, FEA_, HALF_, DM_, 1, FEA_, 0, 32);

  attn_mfma_kernel<<<dim3(8, 16, 32), 256, 0, stream>>>(qhb, khb, vhb, qlb, klb, vlb, ctx);

  // fused wtrans for uns/cv1/cv2/up1/up2 (qkv space now dead)
  WT5 p;
  int base = 0;
  auto seg = [&](int i, const float* src, u16* dst, int cout, int cin) {
    p.s[i] = {src, dst, cout, cin, base};
    base += cout * cin * 3;
  };
  seg(0, uns_w, wt_uns, FEA_, 2 * FEA_);
  seg(1, cv_w1, wt_cv1, DFF_, DM_);
  seg(2, cv_w2, wt_cv2, HALF_, DFF_);
  seg(3, up_w1, wt_up1, DFF_, HALF_);
  seg(4, up_w2, wt_up2, DM_, DFF_);
  p.total = base;
  wtrans5_kernel<<<(p.total + 255) / 256, 256, 0, stream>>>(p);

  // unsqueeze conv: conv along d axis, channels 2F->F, transposed write -> ctx2[b][f][d]
  conv(ctx, wt_uns, uns_b, ctx2, DM_, 2 * FEA_, FEA_, 1, DM_, 0, B_);

  // Convlayer: D_MODEL -> D_FF -> HALF (conv along fea axis), then LN
  conv(ctx2, wt_cv1, cv_b1, h1, FEA_, DM_, DFF_, DFF_, 1, 1, B_);
  conv(h1, wt_cv2, cv_b2, h2, FEA_, DFF_, HALF_, HALF_, 1, 0, B_);
  ln_kernel<0><<<B_ * FEA_, 256, 0, stream>>>(h2, cv_g, cv_beta, nullptr, ctx3, HALF_);

  // upsizeConvlayer: HALF -> D_FF -> D_MODEL, then LN + residual
  conv(ctx3, wt_up1, up_b1, h3, FEA_, HALF_, DFF_, DFF_, 1, 1, B_);
  conv(h3, wt_up2, up_b2, h4, FEA_, DFF_, DM_, DM_, 1, 0, B_);
  ln_kernel<1><<<B_ * FEA_, 256, 0, stream>>>(h4, up_g, up_beta, x, d_out, DM_);
}

// Round 15
// 663.555 us; speedup vs baseline: 1.7822x; 1.0746x over previous
//
#include <hip/hip_runtime.h>
#include <hip/hip_bf16.h>

#define B_    16
#define FEA_  512
#define DM_   1024
#define HALF_ 512
#define DFF_  2048

typedef unsigned short u16;
typedef __attribute__((ext_vector_type(8))) short bf16x8;
typedef __attribute__((ext_vector_type(4))) float f32x4;

__device__ __forceinline__ float bf2f(u16 u) {
  union { unsigned int i; float f; } v; v.i = ((unsigned int)u) << 16; return v.f;
}
__device__ __forceinline__ u16 f2bf(float f) {
  union { float f; unsigned int i; } v; v.f = f;
  unsigned int x = v.i;
  return (u16)((x + 0x7fffu + ((x >> 16) & 1u)) >> 16);
}
__device__ __forceinline__ void gload16(const u16* g, u16* l) {
  __builtin_amdgcn_global_load_lds(
      (const __attribute__((address_space(1))) void*)g,
      (__attribute__((address_space(3))) void*)l, 16, 0, 0);
}

// ---------------- DWT (Haar, level 1, last axis) ----------------
__global__ void dwt_kernel(const float* __restrict__ x, u16* __restrict__ x1,
                           u16* __restrict__ x2, int n) {
  int i = blockIdx.x * 256 + threadIdx.x;
  if (i >= n) return;
  float2 v = ((const float2*)x)[i];
  x1[i] = f2bf((v.x + v.y) * 0.70710678118f);
  x2[i] = f2bf((v.x - v.y) * 0.70710678118f);
}

// ---------------- weight transpose, fused variants ----------------
__global__ void wtrans3_kernel(const float* __restrict__ w0, const float* __restrict__ w1,
                               const float* __restrict__ w2, u16* __restrict__ wt,
                               int Cout, int Cin) {
  int n = Cout * Cin * 3;
  int e = blockIdx.x * 256 + threadIdx.x;
  if (e >= 3 * n) return;
  int i = e / n, le = e - i * n;
  const float* w = (i == 0) ? w0 : ((i == 1) ? w1 : w2);
  int co = le / (Cin * 3);
  int r  = le - co * Cin * 3;
  int ci = r / 3;
  int t  = r - ci * 3;
  wt[(size_t)i * n + ((size_t)t * Cout + co) * Cin + ci] = f2bf(w[le]);
}

struct WTSeg { const float* src; u16* dst; int cout, cin, base; };
struct WT5 { WTSeg s[5]; int total; };
__global__ void wtrans5_kernel(WT5 p) {
  int e = blockIdx.x * 256 + threadIdx.x;
  if (e >= p.total) return;
#pragma unroll
  for (int i = 0; i < 5; ++i) {
    int Cin = p.s[i].cin, Cout = p.s[i].cout;
    int n = Cout * Cin * 3;
    int le = e - p.s[i].base;
    if (le >= 0 && le < n) {
      int co = le / (Cin * 3);
      int r  = le - co * Cin * 3;
      int ci = r / 3;
      int t  = r - ci * 3;
      p.s[i].dst[((size_t)t * Cout + co) * Cin + ci] = f2bf(p.s[i].src[le]);
    }
  }
}

// ---------------- circular conv1d (k=3) as MFMA GEMM ----------------
// r12-verified counted-vmcnt rotation, refined (r15):
//  - tap-unrolled group loop: t and buffer indices are literals
//  - W(k+2) issued at TOP of chunk (post-wait): headroom = 2 compute phases
//  - t=2 chunk preloads its A-frags to regs, then (sched_barrier, lgkmcnt(0),
//    s_barrier) -> Z for the NEXT ci-group issues a full compute phase early,
//    hiding Z latency under the t=2 MFMAs.
// FIFO at every chunk's wait: [W(k) (+Z), W(k+1)] -> vmcnt(4) retires W(k)+Z.
#define ZS_GLOAD(c0_)                                                        \
  {                                                                          \
    _Pragma("unroll") for (int i_ = 0; i_ < 5; ++i_) {                       \
      int e_ = tid + i_ * 256;                                               \
      if (e_ < 130 * 8) {                                                    \
        int r_ = e_ >> 3, c_ = e_ & 7;                                       \
        int gl_ = l0 + r_ - 1;                                               \
        if (gl_ < 0) gl_ += L; else if (gl_ >= L) gl_ -= L;                  \
        gload16(Zb + (size_t)gl_ * Cin + (c0_) + ((c_ ^ (r_ & 7)) * 8),      \
                smem + ((size_t)(i_ * 256 + (tid & 192)) * 8));              \
      }                                                                      \
    }                                                                        \
  }
#define WS_ISSUE(t_, c0_, buf_)                                              \
  {                                                                          \
    const u16* Wg_ = Wt + ((size_t)(t_) * Cout + co0) * Cin + (c0_);         \
    int c_ = lane & 7;                                                       \
    _Pragma("unroll") for (int i_ = 0; i_ < 4; ++i_) {                       \
      int rw_ = (i_ * 4 + w) * 8 + (lane >> 3);                              \
      gload16(Wg_ + (size_t)rw_ * Cin + ((c_ ^ (rw_ & 7)) * 8),              \
              &Wb[(buf_)][(i_ * 4 + w) * 8][0]);                             \
    }                                                                        \
  }
// compute one chunk, tap t_ (literal), weights from Wb[buf_]
#define COMPUTE(t_, buf_)                                                    \
  {                                                                          \
    _Pragma("unroll") for (int ks = 0; ks < 2; ++ks) {                       \
      int s = ks * 4 + g4;                                                   \
      bf16x8 af[4], bfr[4];                                                  \
      _Pragma("unroll") for (int mi = 0; mi < 4; ++mi) {                     \
        int ra = wr * 64 + mi * 16 + row16 + (t_);                           \
        af[mi] = *(const bf16x8*)&Zs[ra][(s ^ (ra & 7)) * 8];                \
      }                                                                      \
      _Pragma("unroll") for (int ni = 0; ni < 4; ++ni) {                     \
        int rb = wc * 64 + ni * 16 + row16;                                  \
        bfr[ni] = *(const bf16x8*)&Wb[(buf_)][rb][(s ^ (rb & 7)) * 8];       \
      }                                                                      \
      __builtin_amdgcn_s_setprio(1);                                         \
      _Pragma("unroll") for (int mi = 0; mi < 4; ++mi)                       \
        _Pragma("unroll") for (int ni = 0; ni < 4; ++ni)                     \
          acc[mi][ni] = __builtin_amdgcn_mfma_f32_16x16x32_bf16(             \
              af[mi], bfr[ni], acc[mi][ni], 0, 0, 0);                        \
      __builtin_amdgcn_s_setprio(0);                                         \
    }                                                                        \
  }
// compute tap 2 from preloaded A-frags (af2[8], static indices)
#define COMPUTE2_REG(buf_)                                                   \
  {                                                                          \
    _Pragma("unroll") for (int ks = 0; ks < 2; ++ks) {                       \
      int s = ks * 4 + g4;                                                   \
      bf16x8 bfr[4];                                                         \
      _Pragma("unroll") for (int ni = 0; ni < 4; ++ni) {                     \
        int rb = wc * 64 + ni * 16 + row16;                                  \
        bfr[ni] = *(const bf16x8*)&Wb[(buf_)][rb][(s ^ (rb & 7)) * 8];       \
      }                                                                      \
      __builtin_amdgcn_s_setprio(1);                                         \
      _Pragma("unroll") for (int mi = 0; mi < 4; ++mi)                       \
        _Pragma("unroll") for (int ni = 0; ni < 4; ++ni)                     \
          acc[mi][ni] = __builtin_amdgcn_mfma_f32_16x16x32_bf16(             \
              af2[ks * 4 + mi], bfr[ni], acc[mi][ni], 0, 0, 0);              \
      __builtin_amdgcn_s_setprio(0);                                         \
    }                                                                        \
  }
#define WAIT4 { asm volatile("s_waitcnt vmcnt(4)" ::: "memory");             \
                __builtin_amdgcn_s_barrier(); }

__global__ __launch_bounds__(256, 2) void conv_mfma_kernel(
    const u16* __restrict__ Z, const u16* __restrict__ Wt,
    const float* __restrict__ bias, u16* __restrict__ out,
    int L, int Cin, int Cout, int osl, int osc, int relu) {
  __shared__ __align__(16) u16 smem[130 * 64 + 3 * 128 * 64];
  u16 (*Zs)[64] = (u16(*)[64])smem;                        // [130][64]
  u16 (*Wb)[128][64] = (u16(*)[128][64])(smem + 130 * 64); // [3][128][64]
  int l0 = blockIdx.x * 128, co0 = blockIdx.y * 128, b = blockIdx.z;
  int tid = threadIdx.x;
  int lane = tid & 63, w = tid >> 6, wr = w >> 1, wc = w & 1;
  int row16 = lane & 15, g4 = lane >> 4;
  f32x4 acc[4][4];
#pragma unroll
  for (int i = 0; i < 4; ++i)
#pragma unroll
    for (int j = 0; j < 4; ++j) acc[i][j] = (f32x4){0.f, 0.f, 0.f, 0.f};
  const u16* Zb = Z + (size_t)b * L * Cin;

  int ncg = Cin >> 6;
  ZS_GLOAD(0);
  WS_ISSUE(0, 0, 0);
  WS_ISSUE(1, 0, 1);

  for (int cg = 0; cg < ncg; ++cg) {
    int c0 = cg << 6;
    bool lastg = (cg == ncg - 1);
    // ---- chunk t=0 ----
    WAIT4;
    WS_ISSUE(2, c0, 2);
    COMPUTE(0, 0);
    // ---- chunk t=1 ----
    WAIT4;
    if (!lastg) WS_ISSUE(0, c0 + 64, 0);
    COMPUTE(1, 1);
    // ---- chunk t=2 ----
    if (!lastg) {
      WAIT4;
      bf16x8 af2[8];
#pragma unroll
      for (int ks = 0; ks < 2; ++ks) {
        int s = ks * 4 + g4;
#pragma unroll
        for (int mi = 0; mi < 4; ++mi) {
          int ra = wr * 64 + mi * 16 + row16 + 2;
          af2[ks * 4 + mi] = *(const bf16x8*)&Zs[ra][(s ^ (ra & 7)) * 8];
        }
      }
      __builtin_amdgcn_sched_barrier(0);
      asm volatile("s_waitcnt lgkmcnt(0)" ::: "memory");
      __builtin_amdgcn_s_barrier();          // all waves hold A-frags; Zs dead
      ZS_GLOAD(c0 + 64);                     // next group's Z, a phase early
      WS_ISSUE(1, c0 + 64, 1);
      COMPUTE2_REG(2);
    } else {
      asm volatile("s_waitcnt vmcnt(0)" ::: "memory");
      __builtin_amdgcn_s_barrier();
      COMPUTE(2, 2);
    }
  }

  // ---- coalesced epilogue: stage tile in LDS (row = strided dim) ----
  __syncthreads();
  const int TP = 136;
  u16* tile = smem;
  size_t ob = (size_t)b * L * Cout;
  int S, rowbase, colbase;
  if (osc == 1) { S = osl; rowbase = l0; colbase = co0; }
  else          { S = osc; rowbase = co0; colbase = l0; }
#pragma unroll
  for (int ni = 0; ni < 4; ++ni) {
    int c_loc = wc * 64 + ni * 16 + row16;
    float bz = bias[co0 + c_loc];
#pragma unroll
    for (int mi = 0; mi < 4; ++mi) {
#pragma unroll
      for (int r = 0; r < 4; ++r) {
        int l_loc = wr * 64 + mi * 16 + g4 * 4 + r;
        float v = acc[mi][ni][r] + bz;
        if (relu) v = fmaxf(v, 0.f);
        int row = (osc == 1) ? l_loc : c_loc;
        int col = (osc == 1) ? c_loc : l_loc;
        tile[row * TP + col] = f2bf(v);
      }
    }
  }
  __syncthreads();
  for (int e = tid; e < 128 * 16; e += 256) {
    int row = e >> 4, c8 = (e & 15) * 8;
    *(uint4*)(out + ob + (size_t)(rowbase + row) * S + colbase + c8) =
        *(const uint4*)&tile[row * TP + c8];
  }
}

// ---------------- fused cross attention, MFMA (unchanged) ----------------
__global__ __launch_bounds__(256, 4) void attn_mfma_kernel(
    const u16* __restrict__ qh, const u16* __restrict__ kh, const u16* __restrict__ vhT,
    const u16* __restrict__ ql, const u16* __restrict__ kl, const u16* __restrict__ vlT,
    u16* __restrict__ ctx) {
  __shared__ u16 Qs[64][72], Ks[64][72], Vts[64][72];
  __shared__ u16 Ps[64][72];
  __shared__ float rsl[2][2][32];
  int qt = blockIdx.x, h = blockIdx.y, bz = blockIdx.z;
  int b = bz >> 1, br = bz & 1;
  const u16* Q  = br ? ql  : qh;
  const u16* K  = br ? kh  : kl;
  const u16* Vt = br ? vlT : vhT;
  int tid = threadIdx.x;
  int lane = tid & 63, w = tid >> 6, wr = w >> 1, wc = w & 1;
  int row16 = lane & 15, g4 = lane >> 4, k8 = g4 * 8;
  int q0 = qt * 64;
  size_t baseQK = (size_t)b * FEA_ * DM_ + h * 64;
  size_t baseV  = (size_t)b * DM_ * FEA_ + (size_t)(h * 64) * FEA_;
  for (int e = tid; e < 64 * 8; e += 256) {
    int r = e >> 3, c = e & 7;
    *(uint4*)&Qs[r][c * 8] = *(const uint4*)(Q + baseQK + (size_t)(q0 + r) * DM_ + c * 8);
  }
  f32x4 oacc[2][2];
  float rsum[2][4];
#pragma unroll
  for (int i = 0; i < 2; ++i) {
#pragma unroll
    for (int j = 0; j < 2; ++j) oacc[i][j] = (f32x4){0.f, 0.f, 0.f, 0.f};
#pragma unroll
    for (int r = 0; r < 4; ++r) rsum[i][r] = 0.f;
  }
  for (int kt = 0; kt < 8; ++kt) {
    __syncthreads();
    for (int e = tid; e < 64 * 8; e += 256) {
      int r = e >> 3, c = e & 7;
      *(uint4*)&Ks[r][c * 8]  = *(const uint4*)(K + baseQK + (size_t)(kt * 64 + r) * DM_ + c * 8);
      *(uint4*)&Vts[r][c * 8] = *(const uint4*)(Vt + baseV + (size_t)r * FEA_ + kt * 64 + c * 8);
    }
    __syncthreads();
    f32x4 sacc[2][2];
#pragma unroll
    for (int i = 0; i < 2; ++i)
#pragma unroll
      for (int j = 0; j < 2; ++j) sacc[i][j] = (f32x4){0.f, 0.f, 0.f, 0.f};
#pragma unroll
    for (int ks = 0; ks < 2; ++ks) {
      int k0 = ks * 32 + k8;
      bf16x8 a0 = *(const bf16x8*)&Qs[wr * 32 + row16][k0];
      bf16x8 a1 = *(const bf16x8*)&Qs[wr * 32 + 16 + row16][k0];
      bf16x8 b0 = *(const bf16x8*)&Ks[wc * 32 + row16][k0];
      bf16x8 b1 = *(const bf16x8*)&Ks[wc * 32 + 16 + row16][k0];
      sacc[0][0] = __builtin_amdgcn_mfma_f32_16x16x32_bf16(a0, b0, sacc[0][0], 0, 0, 0);
      sacc[0][1] = __builtin_amdgcn_mfma_f32_16x16x32_bf16(a0, b1, sacc[0][1], 0, 0, 0);
      sacc[1][0] = __builtin_amdgcn_mfma_f32_16x16x32_bf16(a1, b0, sacc[1][0], 0, 0, 0);
      sacc[1][1] = __builtin_amdgcn_mfma_f32_16x16x32_bf16(a1, b1, sacc[1][1], 0, 0, 0);
    }
#pragma unroll
    for (int mi = 0; mi < 2; ++mi)
#pragma unroll
      for (int ni = 0; ni < 2; ++ni)
#pragma unroll
        for (int r = 0; r < 4; ++r) {
          float p = __expf(sacc[mi][ni][r] * 0.25f);
          rsum[mi][r] += p;
          Ps[wr * 32 + mi * 16 + g4 * 4 + r][wc * 32 + ni * 16 + row16] = f2bf(p);
        }
    __syncthreads();
#pragma unroll
    for (int ks = 0; ks < 2; ++ks) {
      int k0 = ks * 32 + k8;
      bf16x8 a0 = *(const bf16x8*)&Ps[wr * 32 + row16][k0];
      bf16x8 a1 = *(const bf16x8*)&Ps[wr * 32 + 16 + row16][k0];
      bf16x8 b0 = *(const bf16x8*)&Vts[wc * 32 + row16][k0];
      bf16x8 b1 = *(const bf16x8*)&Vts[wc * 32 + 16 + row16][k0];
      oacc[0][0] = __builtin_amdgcn_mfma_f32_16x16x32_bf16(a0, b0, oacc[0][0], 0, 0, 0);
      oacc[0][1] = __builtin_amdgcn_mfma_f32_16x16x32_bf16(a0, b1, oacc[0][1], 0, 0, 0);
      oacc[1][0] = __builtin_amdgcn_mfma_f32_16x16x32_bf16(a1, b0, oacc[1][0], 0, 0, 0);
      oacc[1][1] = __builtin_amdgcn_mfma_f32_16x16x32_bf16(a1, b1, oacc[1][1], 0, 0, 0);
    }
  }
#pragma unroll
  for (int mi = 0; mi < 2; ++mi)
#pragma unroll
    for (int r = 0; r < 4; ++r) {
#pragma unroll
      for (int m = 1; m < 16; m <<= 1) rsum[mi][r] += __shfl_xor(rsum[mi][r], m);
    }
  if (row16 == 0) {
#pragma unroll
    for (int mi = 0; mi < 2; ++mi)
#pragma unroll
      for (int r = 0; r < 4; ++r) rsl[wr][wc][mi * 16 + g4 * 4 + r] = rsum[mi][r];
  }
  __syncthreads();
#pragma unroll
  for (int mi = 0; mi < 2; ++mi)
#pragma unroll
    for (int ni = 0; ni < 2; ++ni)
#pragma unroll
      for (int r = 0; r < 4; ++r) {
        int qq = mi * 16 + g4 * 4 + r;
        float denom = rsl[wr][0][qq] + rsl[wr][1][qq];
        float o = oacc[mi][ni][r] / denom;
        Ps[wc * 32 + ni * 16 + row16][wr * 32 + qq] = f2bf(o);
      }
  __syncthreads();
  for (int e = tid; e < 64 * 8; e += 256) {
    int r = e >> 3, c = e & 7;
    size_t dst = ((size_t)b * DM_ + h * 64 + r) * (2 * FEA_) + br * 512 + q0 + c * 8;
    *(uint4*)(ctx + dst) = *(const uint4*)&Ps[r][c * 8];
  }
}

// ---------------- LayerNorm over last axis, vectorized ----------------
template <int RESID>
__global__ void ln_kernel(const u16* __restrict__ in, const float* __restrict__ g,
                          const float* __restrict__ beta, const float* __restrict__ resid,
                          void* __restrict__ outp, int C) {
  int row = blockIdx.x;
  int tid = threadIdx.x;
  const u16* p = in + (size_t)row * C;
  float s = 0.f, ss = 0.f;
  for (int c = tid * 4; c < C; c += 1024) {
    ushort4 u = *(const ushort4*)(p + c);
    float v0 = bf2f(u.x), v1 = bf2f(u.y), v2 = bf2f(u.z), v3 = bf2f(u.w);
    s += v0 + v1 + v2 + v3;
    ss += v0 * v0 + v1 * v1 + v2 * v2 + v3 * v3;
  }
#pragma unroll
  for (int m = 1; m < 64; m <<= 1) { s += __shfl_xor(s, m); ss += __shfl_xor(ss, m); }
  __shared__ float red[2][4];
  int wid = tid >> 6, lane = tid & 63;
  if (lane == 0) { red[0][wid] = s; red[1][wid] = ss; }
  __syncthreads();
  s  = red[0][0] + red[0][1] + red[0][2] + red[0][3];
  ss = red[1][0] + red[1][1] + red[1][2] + red[1][3];
  float m  = s / C;
  float var = ss / C - m * m;
  float inv = rsqrtf(var + 1e-5f);
  for (int c = tid * 4; c < C; c += 1024) {
    ushort4 u = *(const ushort4*)(p + c);
    float4 gg = *(const float4*)(g + c);
    float4 bb = *(const float4*)(beta + c);
    float v0 = (bf2f(u.x) - m) * inv * gg.x + bb.x;
    float v1 = (bf2f(u.y) - m) * inv * gg.y + bb.y;
    float v2 = (bf2f(u.z) - m) * inv * gg.z + bb.z;
    float v3 = (bf2f(u.w) - m) * inv * gg.w + bb.w;
    if (RESID) {
      float4 rr = *(const float4*)(resid + (size_t)row * C + c);
      float4 o = {v0 + rr.x, v1 + rr.y, v2 + rr.z, v3 + rr.w};
      *(float4*)((float*)outp + (size_t)row * C + c) = o;
    } else {
      ushort4 o = {f2bf(v0), f2bf(v1), f2bf(v2), f2bf(v3)};
      *(ushort4*)((u16*)outp + (size_t)row * C + c) = o;
    }
  }
}

extern "C" void kernel_launch(void* const* d_in, const int* in_sizes, int n_in,
                              void* d_out, int out_size, void* d_ws, size_t ws_size,
                              hipStream_t stream) {
  (void)in_sizes; (void)n_in; (void)out_size; (void)ws_size;
  const float* x      = (const float*)d_in[0];
  const float* Wq     = (const float*)d_in[1];
  const float* bq     = (const float*)d_in[2];
  const float* Wk     = (const float*)d_in[3];
  const float* bk     = (const float*)d_in[4];
  const float* Wv     = (const float*)d_in[5];
  const float* bv     = (const float*)d_in[6];
  const float* uns_w  = (const float*)d_in[7];
  const float* uns_b  = (const float*)d_in[8];
  const float* cv_w1  = (const float*)d_in[9];
  const float* cv_b1  = (const float*)d_in[10];
  const float* cv_w2  = (const float*)d_in[11];
  const float* cv_b2  = (const float*)d_in[12];
  const float* cv_g   = (const float*)d_in[13];
  const float* cv_beta= (const float*)d_in[14];
  const float* up_w1  = (const float*)d_in[15];
  const float* up_b1  = (const float*)d_in[16];
  const float* up_w2  = (const float*)d_in[17];
  const float* up_b2  = (const float*)d_in[18];
  const float* up_g   = (const float*)d_in[19];
  const float* up_beta= (const float*)d_in[20];

  // ---- workspace plan (peak 112 MiB; d_out doubles as scratch) ----
  char* ws = (char*)d_ws;
  const size_t MB = 1ull << 20;
  u16* x1    = (u16*)(ws + 0);
  u16* x1x2  = x1;
  u16* qhb   = (u16*)(ws + 16 * MB);
  u16* khb   = (u16*)(ws + 48 * MB);
  u16* vhb   = (u16*)(ws + 80 * MB);
  u16* qlb   = (u16*)(ws + 32 * MB);
  u16* klb   = (u16*)(ws + 64 * MB);
  u16* vlb   = (u16*)(ws + 96 * MB);
  u16* wt_proj = (u16*)d_out;
  u16* ctx   = (u16*)d_out;
  u16* wt_uns  = (u16*)(ws + 0);
  u16* wt_cv1  = (u16*)(ws + 4 * MB);
  u16* wt_cv2  = (u16*)(ws + 17 * MB);
  u16* wt_up1  = (u16*)(ws + 24 * MB);
  u16* wt_up2  = (u16*)(ws + 31 * MB);
  u16* ctx2  = (u16*)(ws + 48 * MB);
  u16* h1    = (u16*)(ws + 64 * MB);
  u16* h2    = (u16*)(ws + 96 * MB);
  u16* ctx3  = (u16*)(ws + 104 * MB);
  u16* h3    = (u16*)(ws + 64 * MB);
  u16* h4    = (u16*)(ws + 48 * MB);

  dwt_kernel<<<(B_ * FEA_ * HALF_ + 255) / 256, 256, 0, stream>>>(x, x1, (u16*)(ws + 8 * MB),
                                                                  B_ * FEA_ * HALF_);

  const int NPROJ = DM_ * HALF_ * 3;
  wtrans3_kernel<<<(3 * NPROJ + 255) / 256, 256, 0, stream>>>(Wq, Wk, Wv, wt_proj, DM_, HALF_);

  auto conv = [&](const u16* Z, const u16* wt, const float* bias, u16* out, int L,
                  int Cin, int Cout, int osl, int osc, int relu, int nb) {
    conv_mfma_kernel<<<dim3(L / 128, Cout / 128, nb), 256, 0, stream>>>(
        Z, wt, bias, out, L, Cin, Cout, osl, osc, relu);
  };

  // projections, both DWT branches batched (B=32); V written transposed
  conv(x1x2, wt_proj,              bq, qhb, FEA_, HALF_, DM_, DM_, 1, 0, 32);
  conv(x1x2, wt_proj + NPROJ,      bk, khb, FEA_, HALF_, DM_, DM_, 1, 0, 32);
  conv(x1x2, wt_proj + 2 * NPROJ,  bv, vhb, FEA_, HALF_, DM_, 1, FEA_, 0, 32);

  attn_mfma_kernel<<<dim3(8, 16, 32), 256, 0, stream>>>(qhb, khb, vhb, qlb, klb, vlb, ctx);

  WT5 p;
  int base = 0;
  auto seg = [&](int i, const float* src, u16* dst, int cout, int cin) {
    p.s[i] = {src, dst, cout, cin, base};
    base += cout * cin * 3;
  };
  seg(0, uns_w, wt_uns, FEA_, 2 * FEA_);
  seg(1, cv_w1, wt_cv1, DFF_, DM_);
  seg(2, cv_w2, wt_cv2, HALF_, DFF_);
  seg(3, up_w1, wt_up1, DFF_, HALF_);
  seg(4, up_w2, wt_up2, DM_, DFF_);
  p.total = base;
  wtrans5_kernel<<<(p.total + 255) / 256, 256, 0, stream>>>(p);

  conv(ctx, wt_uns, uns_b, ctx2, DM_, 2 * FEA_, FEA_, 1, DM_, 0, B_);

  conv(ctx2, wt_cv1, cv_b1, h1, FEA_, DM_, DFF_, DFF_, 1, 1, B_);
  conv(h1, wt_cv2, cv_b2, h2, FEA_, DFF_, HALF_, HALF_, 1, 0, B_);
  ln_kernel<0><<<B_ * FEA_, 256, 0, stream>>>(h2, cv_g, cv_beta, nullptr, ctx3, HALF_);

  conv(ctx3, wt_up1, up_b1, h3, FEA_, HALF_, DFF_, DFF_, 1, 1, B_);
  conv(h3, wt_up2, up_b2, h4, FEA_, DFF_, DM_, DM_, 1, 0, B_);
  ln_kernel<1><<<B_ * FEA_, 256, 0, stream>>>(h4, up_g, up_beta, x, d_out, DM_);
}